// Round 1
// baseline (7681.482 us; speedup 1.0000x reference)
//
#include <hip/hip_runtime.h>
#include <math.h>

#define D64 64

// --- helpers -------------------------------------------------------------

__device__ __forceinline__ float rl(float v, int k) {
    // broadcast lane k's value to all lanes as a uniform (v_readlane -> SGPR)
    return __uint_as_float((unsigned)__builtin_amdgcn_readlane((int)__float_as_uint(v), k));
}

__device__ __forceinline__ float wave_sum64(float v) {
    v += __shfl_xor(v, 32, 64);
    v += __shfl_xor(v, 16, 64);
    v += __shfl_xor(v, 8, 64);
    v += __shfl_xor(v, 4, 64);
    v += __shfl_xor(v, 2, 64);
    v += __shfl_xor(v, 1, 64);
    return v;
}

__device__ __forceinline__ float sigm(float z) { return 1.0f / (1.0f + __expf(-z)); }
__device__ __forceinline__ float silu(float z) { return z * sigm(z); }

// --- kernel A: init ws + x_out ------------------------------------------

__global__ void init_kernel(const float* __restrict__ x,
                            float* __restrict__ node_msg,
                            float* __restrict__ xout, int N) {
    int i = blockIdx.x * blockDim.x + threadIdx.x;
    if (i < N * 64) node_msg[i] = 0.0f;
    if (i < N * 3)  xout[i] = x[i];
}

// --- kernel B: per-edge pipeline ----------------------------------------
// wave = 64 lanes; lane j owns feature j; 4 edges per wave-iteration.
// LDS: Wm1 [192][64] + Wm2 [64][64] = 64 KB (2 blocks/CU at 160 KB LDS).

__global__ __launch_bounds__(512, 4)
void edge_kernel(const float* __restrict__ h, const float* __restrict__ x,
                 const int* __restrict__ edst, const int* __restrict__ esrc,
                 const float* __restrict__ means, const float* __restrict__ stds,
                 const float* __restrict__ Wm1, const float* __restrict__ bm1,
                 const float* __restrict__ Wm2, const float* __restrict__ bm2,
                 const float* __restrict__ Wa, const float* __restrict__ ba,
                 const float* __restrict__ Wx1, const float* __restrict__ bx1,
                 const float* __restrict__ Wx2,
                 float* __restrict__ node_msg, float* __restrict__ xout,
                 int E)
{
    __shared__ float sW[192 * 64 + 64 * 64];   // 65536 B exactly
    float* sWm1 = sW;
    float* sWm2 = sW + 192 * 64;
    for (int i = threadIdx.x; i < 192 * 64; i += blockDim.x) sWm1[i] = Wm1[i];
    for (int i = threadIdx.x; i < 64 * 64;  i += blockDim.x) sWm2[i] = Wm2[i];
    __syncthreads();

    const int lane = threadIdx.x & 63;
    const int wid  = (blockIdx.x * blockDim.x + threadIdx.x) >> 6;
    const int nw   = (gridDim.x * blockDim.x) >> 6;

    // per-lane loop invariants
    const float bm1_l = bm1[lane];
    const float bm2_l = bm2[lane];
    const float bx1_l = bx1[lane];
    const float Wa_l  = Wa[lane];
    const float Wx2_l = Wx2[lane];
    const float ba_s  = ba[0];
    const float mean_l = means[lane];
    const float istd_l = 1.0f / stds[lane];

    for (int base = wid * 4; base < E; base += nw * 4) {
        int dst[4], src[4];
        float hd[4], hs[4], rbf[4], dirx[4], diry[4], dirz[4], msk[4];

        #pragma unroll
        for (int i = 0; i < 4; ++i) {
            int e = base + i;
            bool valid = (e < E);
            if (!valid) e = base;               // duplicate; contributions zeroed via msk
            dst[i] = edst[e];
            src[i] = esrc[e];
            hd[i] = h[(size_t)dst[i] * 64 + lane];
            hs[i] = h[(size_t)src[i] * 64 + lane];
            float dx = x[dst[i] * 3 + 0] - x[src[i] * 3 + 0];
            float dy = x[dst[i] * 3 + 1] - x[src[i] * 3 + 1];
            float dz = x[dst[i] * 3 + 2] - x[src[i] * 3 + 2];
            float d2 = dx * dx + dy * dy + dz * dz;
            float dist = sqrtf(d2);
            float inv  = 1.0f / dist;
            dirx[i] = dx * inv; diry[i] = dy * inv; dirz[i] = dz * inv;
            msk[i] = (valid && dist <= 3.0f) ? 1.0f : 0.0f;
            float t = (dist - mean_l) * istd_l;
            rbf[i] = __expf(-0.5f * t * t);
        }

        // ---- m1 = silu(inp @ Wm1 + bm1), inp = [h_dst | h_src | rbf] ----
        float acc[4] = {bm1_l, bm1_l, bm1_l, bm1_l};
        #pragma unroll
        for (int k = 0; k < 64; ++k) {
            float w = sWm1[k * 64 + lane];
            acc[0] = fmaf(rl(hd[0], k), w, acc[0]);
            acc[1] = fmaf(rl(hd[1], k), w, acc[1]);
            acc[2] = fmaf(rl(hd[2], k), w, acc[2]);
            acc[3] = fmaf(rl(hd[3], k), w, acc[3]);
        }
        #pragma unroll
        for (int k = 0; k < 64; ++k) {
            float w = sWm1[(64 + k) * 64 + lane];
            acc[0] = fmaf(rl(hs[0], k), w, acc[0]);
            acc[1] = fmaf(rl(hs[1], k), w, acc[1]);
            acc[2] = fmaf(rl(hs[2], k), w, acc[2]);
            acc[3] = fmaf(rl(hs[3], k), w, acc[3]);
        }
        #pragma unroll
        for (int k = 0; k < 64; ++k) {
            float w = sWm1[(128 + k) * 64 + lane];
            acc[0] = fmaf(rl(rbf[0], k), w, acc[0]);
            acc[1] = fmaf(rl(rbf[1], k), w, acc[1]);
            acc[2] = fmaf(rl(rbf[2], k), w, acc[2]);
            acc[3] = fmaf(rl(rbf[3], k), w, acc[3]);
        }
        float m1v[4];
        #pragma unroll
        for (int i = 0; i < 4; ++i) m1v[i] = silu(acc[i]);

        // ---- m2 = silu(m1 @ Wm2 + bm2) ----
        float acc2[4] = {bm2_l, bm2_l, bm2_l, bm2_l};
        #pragma unroll
        for (int k = 0; k < 64; ++k) {
            float w = sWm2[k * 64 + lane];
            acc2[0] = fmaf(rl(m1v[0], k), w, acc2[0]);
            acc2[1] = fmaf(rl(m1v[1], k), w, acc2[1]);
            acc2[2] = fmaf(rl(m1v[2], k), w, acc2[2]);
            acc2[3] = fmaf(rl(m1v[3], k), w, acc2[3]);
        }
        float mm[4];
        #pragma unroll
        for (int i = 0; i < 4; ++i) {
            float m2v = silu(acc2[i]);
            float att = sigm(wave_sum64(m2v * Wa_l) + ba_s);
            mm[i] = m2v * att * msk[i];          // pruned/invalid edges -> 0
        }

        // ---- scatter messages ----
        #pragma unroll
        for (int i = 0; i < 4; ++i)
            unsafeAtomicAdd(&node_msg[(size_t)dst[i] * 64 + lane], mm[i]);

        // ---- x branch: tanh(silu(m @ Wx1 + bx1) @ Wx2) ----
        float acc3[4] = {bx1_l, bx1_l, bx1_l, bx1_l};
        #pragma unroll
        for (int k = 0; k < 64; ++k) {
            float w = Wx1[k * 64 + lane];        // global, L1-resident (16 KB)
            acc3[0] = fmaf(rl(mm[0], k), w, acc3[0]);
            acc3[1] = fmaf(rl(mm[1], k), w, acc3[1]);
            acc3[2] = fmaf(rl(mm[2], k), w, acc3[2]);
            acc3[3] = fmaf(rl(mm[3], k), w, acc3[3]);
        }
        #pragma unroll
        for (int i = 0; i < 4; ++i) {
            float t = silu(acc3[i]);
            float mag = tanhf(wave_sum64(t * Wx2_l)) * msk[i];
            if (lane < 3) {
                float dc = (lane == 0) ? dirx[i] : ((lane == 1) ? diry[i] : dirz[i]);
                unsafeAtomicAdd(&xout[(size_t)dst[i] * 3 + lane], dc * mag);
            }
        }
    }
}

// --- kernel C: node update ----------------------------------------------

__global__ __launch_bounds__(512, 4)
void node_kernel(const float* __restrict__ h, const float* __restrict__ node_msg,
                 const float* __restrict__ Wh1, const float* __restrict__ bh1,
                 const float* __restrict__ Wh2, const float* __restrict__ bh2,
                 float* __restrict__ hout, int N)
{
    __shared__ float sW[128 * 64 + 64 * 64];   // 49152 B
    float* sWh1 = sW;
    float* sWh2 = sW + 128 * 64;
    for (int i = threadIdx.x; i < 128 * 64; i += blockDim.x) sWh1[i] = Wh1[i];
    for (int i = threadIdx.x; i < 64 * 64;  i += blockDim.x) sWh2[i] = Wh2[i];
    __syncthreads();

    const int lane = threadIdx.x & 63;
    const int wid  = (blockIdx.x * blockDim.x + threadIdx.x) >> 6;
    const int nw   = (gridDim.x * blockDim.x) >> 6;

    const float bh1_l = bh1[lane];
    const float bh2_l = bh2[lane];

    for (int n = wid; n < N; n += nw) {
        float hn  = h[(size_t)n * 64 + lane];
        float mg  = node_msg[(size_t)n * 64 + lane];

        float acc = bh1_l;
        #pragma unroll
        for (int k = 0; k < 64; ++k)
            acc = fmaf(rl(hn, k), sWh1[k * 64 + lane], acc);
        #pragma unroll
        for (int k = 0; k < 64; ++k)
            acc = fmaf(rl(mg, k), sWh1[(64 + k) * 64 + lane], acc);
        float t = silu(acc);

        float acc2 = bh2_l;
        #pragma unroll
        for (int k = 0; k < 64; ++k)
            acc2 = fmaf(rl(t, k), sWh2[k * 64 + lane], acc2);

        hout[(size_t)n * 64 + lane] = hn + acc2;
    }
}

// --- launch --------------------------------------------------------------

extern "C" void kernel_launch(void* const* d_in, const int* in_sizes, int n_in,
                              void* d_out, int out_size, void* d_ws, size_t ws_size,
                              hipStream_t stream) {
    const float* h    = (const float*)d_in[0];
    const float* x    = (const float*)d_in[1];
    const int*   edst = (const int*)d_in[2];
    const int*   esrc = (const int*)d_in[3];
    const float* means= (const float*)d_in[4];
    const float* stds = (const float*)d_in[5];
    const float* Wm1  = (const float*)d_in[6];
    const float* bm1  = (const float*)d_in[7];
    const float* Wm2  = (const float*)d_in[8];
    const float* bm2  = (const float*)d_in[9];
    const float* Wa   = (const float*)d_in[10];
    const float* ba   = (const float*)d_in[11];
    const float* Wx1  = (const float*)d_in[12];
    const float* bx1  = (const float*)d_in[13];
    const float* Wx2  = (const float*)d_in[14];
    const float* Wh1  = (const float*)d_in[15];
    const float* bh1  = (const float*)d_in[16];
    const float* Wh2  = (const float*)d_in[17];
    const float* bh2  = (const float*)d_in[18];

    const int N = in_sizes[0] / 64;
    const int E = in_sizes[2];

    float* hout = (float*)d_out;
    float* xout = hout + (size_t)N * 64;
    float* node_msg = (float*)d_ws;           // N*64 floats = 12.8 MB

    {
        int thr = 256;
        int blk = (N * 64 + thr - 1) / thr;
        init_kernel<<<blk, thr, 0, stream>>>(x, node_msg, xout, N);
    }
    edge_kernel<<<1024, 512, 0, stream>>>(h, x, edst, esrc, means, stds,
                                          Wm1, bm1, Wm2, bm2, Wa, ba,
                                          Wx1, bx1, Wx2, node_msg, xout, E);
    node_kernel<<<512, 512, 0, stream>>>(h, node_msg, Wh1, bh1, Wh2, bh2, hout, N);
}

// Round 2
// 7393.720 us; speedup vs baseline: 1.0389x; 1.0389x over previous
//
#include <hip/hip_runtime.h>
#include <hip/hip_bf16.h>
#include <math.h>
#include <stdint.h>

// --- helpers -------------------------------------------------------------

__device__ __forceinline__ float rl(float v, int k) {
    return __uint_as_float((unsigned)__builtin_amdgcn_readlane((int)__float_as_uint(v), k));
}

__device__ __forceinline__ float wave_sum64(float v) {
    v += __shfl_xor(v, 32, 64);
    v += __shfl_xor(v, 16, 64);
    v += __shfl_xor(v, 8, 64);
    v += __shfl_xor(v, 4, 64);
    v += __shfl_xor(v, 2, 64);
    v += __shfl_xor(v, 1, 64);
    return v;
}

__device__ __forceinline__ float sigm(float z) { return 1.0f / (1.0f + __expf(-z)); }
__device__ __forceinline__ float silu(float z) { return z * sigm(z); }

// --- CSR build ----------------------------------------------------------

__global__ void zero_kernel(int* __restrict__ counts, int N) {
    int i = blockIdx.x * blockDim.x + threadIdx.x;
    if (i < N) counts[i] = 0;
}

__global__ void hist_kernel(const int* __restrict__ edst, int* __restrict__ counts, int E) {
    int e = blockIdx.x * blockDim.x + threadIdx.x;
    if (e < E) atomicAdd(&counts[edst[e]], 1);
}

// single-block exclusive scan over N counts -> off[0..N], cursor copy
__global__ void scan_kernel(const int* __restrict__ counts,
                            int* __restrict__ off, int* __restrict__ cursor, int N) {
    __shared__ int sa[1024], sb[1024];
    __shared__ int carry_s;
    const int tid = threadIdx.x;
    if (tid == 0) carry_s = 0;
    __syncthreads();
    for (int base = 0; base < N; base += 1024) {
        int i = base + tid;
        int v = (i < N) ? counts[i] : 0;
        sa[tid] = v;
        __syncthreads();
        int* cur = sa; int* nxt = sb;
        #pragma unroll
        for (int d = 1; d < 1024; d <<= 1) {
            int t = cur[tid] + ((tid >= d) ? cur[tid - d] : 0);
            nxt[tid] = t;
            __syncthreads();
            int* tmp = cur; cur = nxt; nxt = tmp;
        }
        int inc = cur[tid];
        int exc = inc + carry_s - v;      // carry_s read before update barrier
        if (i < N) { off[i] = exc; cursor[i] = exc; }
        int total = cur[1023];
        __syncthreads();
        if (tid == 0) carry_s += total;
        __syncthreads();
    }
    if (tid == 0) off[N] = carry_s;
}

__global__ void scatter_kernel(const int* __restrict__ edst,
                               int* __restrict__ cursor, int* __restrict__ csr, int E) {
    int e = blockIdx.x * blockDim.x + threadIdx.x;
    if (e < E) {
        int d = edst[e];
        int p = atomicAdd(&cursor[d], 1);
        csr[p] = e;
    }
}

// --- edge kernel: compute per-edge message + displacement ---------------
// wave = 64 lanes; lane j owns feature j; 4 edges per wave-iteration.
// LDS: Wm1[192][64] + Wm2[64][64] + Wx1[64][64] = 80 KB -> 2 blocks/CU.

__global__ __launch_bounds__(512, 4)
void edge_kernel(const float* __restrict__ h, const float* __restrict__ x,
                 const int* __restrict__ edst, const int* __restrict__ esrc,
                 const float* __restrict__ means, const float* __restrict__ stds,
                 const float* __restrict__ Wm1, const float* __restrict__ bm1,
                 const float* __restrict__ Wm2, const float* __restrict__ bm2,
                 const float* __restrict__ Wa, const float* __restrict__ ba,
                 const float* __restrict__ Wx1, const float* __restrict__ bx1,
                 const float* __restrict__ Wx2,
                 __hip_bfloat16* __restrict__ msg, float4* __restrict__ disp,
                 int E)
{
    __shared__ float sW[192 * 64 + 64 * 64 + 64 * 64];   // 81920 B
    float* sWm1 = sW;
    float* sWm2 = sW + 192 * 64;
    float* sWx1 = sW + 256 * 64;
    for (int i = threadIdx.x; i < 192 * 64; i += blockDim.x) sWm1[i] = Wm1[i];
    for (int i = threadIdx.x; i < 64 * 64;  i += blockDim.x) sWm2[i] = Wm2[i];
    for (int i = threadIdx.x; i < 64 * 64;  i += blockDim.x) sWx1[i] = Wx1[i];
    __syncthreads();

    const int lane = threadIdx.x & 63;
    const int wid  = (blockIdx.x * blockDim.x + threadIdx.x) >> 6;
    const int nw   = (gridDim.x * blockDim.x) >> 6;

    const float bm1_l = bm1[lane];
    const float bm2_l = bm2[lane];
    const float bx1_l = bx1[lane];
    const float Wa_l  = Wa[lane];
    const float Wx2_l = Wx2[lane];
    const float ba_s  = ba[0];
    const float mean_l = means[lane];
    const float istd_l = 1.0f / stds[lane];

    for (int base = wid * 4; base < E; base += nw * 4) {
        int dst[4], src[4];
        float hd[4], hs[4], rbf[4], dirx[4], diry[4], dirz[4], msk[4];

        #pragma unroll
        for (int i = 0; i < 4; ++i) {
            int e = base + i;
            bool valid = (e < E);
            if (!valid) e = base;
            dst[i] = edst[e];
            src[i] = esrc[e];
            hd[i] = h[(size_t)dst[i] * 64 + lane];
            hs[i] = h[(size_t)src[i] * 64 + lane];
            float dx = x[dst[i] * 3 + 0] - x[src[i] * 3 + 0];
            float dy = x[dst[i] * 3 + 1] - x[src[i] * 3 + 1];
            float dz = x[dst[i] * 3 + 2] - x[src[i] * 3 + 2];
            float d2 = dx * dx + dy * dy + dz * dz;
            float dist = sqrtf(d2);
            float inv  = 1.0f / dist;
            dirx[i] = dx * inv; diry[i] = dy * inv; dirz[i] = dz * inv;
            msk[i] = (valid && dist <= 3.0f) ? 1.0f : 0.0f;
            float t = (dist - mean_l) * istd_l;
            rbf[i] = __expf(-0.5f * t * t);
        }

        // ---- m1 = silu(inp @ Wm1 + bm1), inp = [h_dst | h_src | rbf] ----
        float acc[4] = {bm1_l, bm1_l, bm1_l, bm1_l};
        #pragma unroll
        for (int k = 0; k < 64; ++k) {
            float w = sWm1[k * 64 + lane];
            acc[0] = fmaf(rl(hd[0], k), w, acc[0]);
            acc[1] = fmaf(rl(hd[1], k), w, acc[1]);
            acc[2] = fmaf(rl(hd[2], k), w, acc[2]);
            acc[3] = fmaf(rl(hd[3], k), w, acc[3]);
        }
        #pragma unroll
        for (int k = 0; k < 64; ++k) {
            float w = sWm1[(64 + k) * 64 + lane];
            acc[0] = fmaf(rl(hs[0], k), w, acc[0]);
            acc[1] = fmaf(rl(hs[1], k), w, acc[1]);
            acc[2] = fmaf(rl(hs[2], k), w, acc[2]);
            acc[3] = fmaf(rl(hs[3], k), w, acc[3]);
        }
        #pragma unroll
        for (int k = 0; k < 64; ++k) {
            float w = sWm1[(128 + k) * 64 + lane];
            acc[0] = fmaf(rl(rbf[0], k), w, acc[0]);
            acc[1] = fmaf(rl(rbf[1], k), w, acc[1]);
            acc[2] = fmaf(rl(rbf[2], k), w, acc[2]);
            acc[3] = fmaf(rl(rbf[3], k), w, acc[3]);
        }
        float m1v[4];
        #pragma unroll
        for (int i = 0; i < 4; ++i) m1v[i] = silu(acc[i]);

        // ---- m2 = silu(m1 @ Wm2 + bm2), attention ----
        float acc2[4] = {bm2_l, bm2_l, bm2_l, bm2_l};
        #pragma unroll
        for (int k = 0; k < 64; ++k) {
            float w = sWm2[k * 64 + lane];
            acc2[0] = fmaf(rl(m1v[0], k), w, acc2[0]);
            acc2[1] = fmaf(rl(m1v[1], k), w, acc2[1]);
            acc2[2] = fmaf(rl(m1v[2], k), w, acc2[2]);
            acc2[3] = fmaf(rl(m1v[3], k), w, acc2[3]);
        }
        float mm[4];
        #pragma unroll
        for (int i = 0; i < 4; ++i) {
            float m2v = silu(acc2[i]);
            float att = sigm(wave_sum64(m2v * Wa_l) + ba_s);
            mm[i] = m2v * att * msk[i];
        }

        // ---- store messages (coalesced, bf16) ----
        #pragma unroll
        for (int i = 0; i < 4; ++i) {
            if (base + i < E)
                msg[(size_t)(base + i) * 64 + lane] = __float2bfloat16(mm[i]);
        }

        // ---- x branch: tanh(silu(m @ Wx1 + bx1) @ Wx2) ----
        float acc3[4] = {bx1_l, bx1_l, bx1_l, bx1_l};
        #pragma unroll
        for (int k = 0; k < 64; ++k) {
            float w = sWx1[k * 64 + lane];
            acc3[0] = fmaf(rl(mm[0], k), w, acc3[0]);
            acc3[1] = fmaf(rl(mm[1], k), w, acc3[1]);
            acc3[2] = fmaf(rl(mm[2], k), w, acc3[2]);
            acc3[3] = fmaf(rl(mm[3], k), w, acc3[3]);
        }
        #pragma unroll
        for (int i = 0; i < 4; ++i) {
            float t = silu(acc3[i]);
            float mag = tanhf(wave_sum64(t * Wx2_l)) * msk[i];
            if (lane == i && base + i < E) {
                disp[base + i] = make_float4(dirx[i] * mag, diry[i] * mag, dirz[i] * mag, 0.0f);
            }
        }
    }
}

// --- node kernel: CSR gather + h MLP + x update -------------------------
// one wave per node; LDS: Wh1[128][64] + Wh2[64][64] = 48 KB -> 3 blocks/CU.

__global__ __launch_bounds__(512, 4)
void node_kernel(const float* __restrict__ h, const float* __restrict__ x,
                 const int* __restrict__ off, const int* __restrict__ csr,
                 const __hip_bfloat16* __restrict__ msg, const float4* __restrict__ disp,
                 const float* __restrict__ Wh1, const float* __restrict__ bh1,
                 const float* __restrict__ Wh2, const float* __restrict__ bh2,
                 float* __restrict__ hout, float* __restrict__ xout, int N)
{
    __shared__ float sW[128 * 64 + 64 * 64];   // 49152 B
    float* sWh1 = sW;
    float* sWh2 = sW + 128 * 64;
    for (int i = threadIdx.x; i < 128 * 64; i += blockDim.x) sWh1[i] = Wh1[i];
    for (int i = threadIdx.x; i < 64 * 64;  i += blockDim.x) sWh2[i] = Wh2[i];
    __syncthreads();

    const int lane = threadIdx.x & 63;
    const int wid  = (blockIdx.x * blockDim.x + threadIdx.x) >> 6;
    if (wid >= N) return;

    const int row = off[wid];
    const int end = off[wid + 1];

    float accm = 0.0f;       // node_msg[wid][lane]
    float dsum = 0.0f;       // lanes 0..2: x displacement component
    for (int idx = row; idx < end; ++idx) {
        int eid = __builtin_amdgcn_readfirstlane(csr[idx]);
        accm += __bfloat162float(msg[(size_t)eid * 64 + lane]);
        if (lane < 3) {
            const float* dp = (const float*)&disp[eid];
            dsum += dp[lane];
        }
    }

    const float hn = h[(size_t)wid * 64 + lane];

    float acc = bh1[lane];
    #pragma unroll
    for (int k = 0; k < 64; ++k)
        acc = fmaf(rl(hn, k), sWh1[k * 64 + lane], acc);
    #pragma unroll
    for (int k = 0; k < 64; ++k)
        acc = fmaf(rl(accm, k), sWh1[(64 + k) * 64 + lane], acc);
    float t = silu(acc);

    float acc2 = bh2[lane];
    #pragma unroll
    for (int k = 0; k < 64; ++k)
        acc2 = fmaf(rl(t, k), sWh2[k * 64 + lane], acc2);

    hout[(size_t)wid * 64 + lane] = hn + acc2;
    if (lane < 3) xout[(size_t)wid * 3 + lane] = x[wid * 3 + lane] + dsum;
}

// --- launch --------------------------------------------------------------

extern "C" void kernel_launch(void* const* d_in, const int* in_sizes, int n_in,
                              void* d_out, int out_size, void* d_ws, size_t ws_size,
                              hipStream_t stream) {
    const float* h    = (const float*)d_in[0];
    const float* x    = (const float*)d_in[1];
    const int*   edst = (const int*)d_in[2];
    const int*   esrc = (const int*)d_in[3];
    const float* means= (const float*)d_in[4];
    const float* stds = (const float*)d_in[5];
    const float* Wm1  = (const float*)d_in[6];
    const float* bm1  = (const float*)d_in[7];
    const float* Wm2  = (const float*)d_in[8];
    const float* bm2  = (const float*)d_in[9];
    const float* Wa   = (const float*)d_in[10];
    const float* ba   = (const float*)d_in[11];
    const float* Wx1  = (const float*)d_in[12];
    const float* bx1  = (const float*)d_in[13];
    const float* Wx2  = (const float*)d_in[14];
    const float* Wh1  = (const float*)d_in[15];
    const float* bh1  = (const float*)d_in[16];
    const float* Wh2  = (const float*)d_in[17];
    const float* bh2  = (const float*)d_in[18];

    const int N = in_sizes[0] / 64;
    const int E = in_sizes[2];

    float* hout = (float*)d_out;
    float* xout = hout + (size_t)N * 64;

    // workspace layout
    int* counts = (int*)d_ws;                                   // N
    int* off    = counts + N;                                   // N+1
    int* cursor = off + N + 1;                                  // N
    int* csr    = cursor + N;                                   // E
    __hip_bfloat16* msg = (__hip_bfloat16*)(((uintptr_t)(csr + E) + 255) & ~(uintptr_t)255);  // E*64 bf16
    float4* disp = (float4*)(((uintptr_t)(msg + (size_t)E * 64) + 255) & ~(uintptr_t)255);    // E float4

    zero_kernel<<<(N + 255) / 256, 256, 0, stream>>>(counts, N);
    hist_kernel<<<(E + 255) / 256, 256, 0, stream>>>(edst, counts, E);
    scan_kernel<<<1, 1024, 0, stream>>>(counts, off, cursor, N);
    scatter_kernel<<<(E + 255) / 256, 256, 0, stream>>>(edst, cursor, csr, E);

    edge_kernel<<<1024, 512, 0, stream>>>(h, x, edst, esrc, means, stds,
                                          Wm1, bm1, Wm2, bm2, Wa, ba,
                                          Wx1, bx1, Wx2, msg, disp, E);
    node_kernel<<<(N + 7) / 8, 512, 0, stream>>>(h, x, off, csr, msg, disp,
                                                 Wh1, bh1, Wh2, bh2, hout, xout, N);
}

// Round 3
// 619.395 us; speedup vs baseline: 12.4016x; 11.9370x over previous
//
#include <hip/hip_runtime.h>
#include <hip/hip_bf16.h>
#include <math.h>
#include <stdint.h>

typedef __attribute__((ext_vector_type(8))) short bf16x8;
typedef __attribute__((ext_vector_type(4))) short short4v;
typedef __attribute__((ext_vector_type(4))) float f32x4;

// --- helpers -------------------------------------------------------------

__device__ __forceinline__ short f2bf(float f) {
    __hip_bfloat16 b = __float2bfloat16(f);
    return *reinterpret_cast<short*>(&b);
}

__device__ __forceinline__ float rl(float v, int k) {
    return __uint_as_float((unsigned)__builtin_amdgcn_readlane((int)__float_as_uint(v), k));
}

__device__ __forceinline__ float sigm(float z) { return 1.0f / (1.0f + __expf(-z)); }
__device__ __forceinline__ float silu(float z) { return z * sigm(z); }

// --- CSR build ----------------------------------------------------------

__global__ void zero_kernel(int* __restrict__ counts, int N) {
    int i = blockIdx.x * blockDim.x + threadIdx.x;
    if (i < N) counts[i] = 0;
}

__global__ void hist_kernel(const int* __restrict__ edst, int* __restrict__ counts, int E) {
    int e = blockIdx.x * blockDim.x + threadIdx.x;
    if (e < E) atomicAdd(&counts[edst[e]], 1);
}

__global__ void scan_kernel(const int* __restrict__ counts,
                            int* __restrict__ off, int* __restrict__ cursor, int N) {
    __shared__ int sa[1024], sb[1024];
    __shared__ int carry_s;
    const int tid = threadIdx.x;
    if (tid == 0) carry_s = 0;
    __syncthreads();
    for (int base = 0; base < N; base += 1024) {
        int i = base + tid;
        int v = (i < N) ? counts[i] : 0;
        sa[tid] = v;
        __syncthreads();
        int* cur = sa; int* nxt = sb;
        #pragma unroll
        for (int d = 1; d < 1024; d <<= 1) {
            int t = cur[tid] + ((tid >= d) ? cur[tid - d] : 0);
            nxt[tid] = t;
            __syncthreads();
            int* tmp = cur; cur = nxt; nxt = tmp;
        }
        int inc = cur[tid];
        int exc = inc + carry_s - v;
        if (i < N) { off[i] = exc; cursor[i] = exc; }
        int total = cur[1023];
        __syncthreads();
        if (tid == 0) carry_s += total;
        __syncthreads();
    }
    if (tid == 0) off[N] = carry_s;
}

__global__ void scatter_kernel(const int* __restrict__ edst,
                               int* __restrict__ cursor, int* __restrict__ csr, int E) {
    int e = blockIdx.x * blockDim.x + threadIdx.x;
    if (e < E) {
        int d = edst[e];
        int p = atomicAdd(&cursor[d], 1);
        csr[p] = e;
    }
}

// --- prestage: h -> bf16 -------------------------------------------------

__global__ void h2bf_kernel(const float* __restrict__ h, short* __restrict__ hb, int n) {
    int i = blockIdx.x * blockDim.x + threadIdx.x;
    if (i < n) hb[i] = f2bf(h[i]);
}

// --- prestage: weights -> MFMA A-fragment order (bf16) -------------------
// frag F = matbase + (c*4 + t)*64 + L ; element j: A[m=L&15][k=(L>>4)*8+j]
//   value = W[(c*32 + (L>>4)*8 + j)*64 + t*16 + (L&15)]
// Wm1: K=192 -> 1536 frags [0,1536); Wm2: 512 [1536,2048); Wx1: 512 [2048,2560)

__global__ void wfrag_kernel(const float* __restrict__ Wm1, const float* __restrict__ Wm2,
                             const float* __restrict__ Wx1, short* __restrict__ out) {
    int F = blockIdx.x * blockDim.x + threadIdx.x;
    if (F >= 2560) return;
    const float* W; int fi;
    if (F < 1536)      { W = Wm1; fi = F; }
    else if (F < 2048) { W = Wm2; fi = F - 1536; }
    else               { W = Wx1; fi = F - 2048; }
    int c = fi >> 8;
    int t = (fi >> 6) & 3;
    int L = fi & 63;
    int m = L & 15, qq = L >> 4;
    short tmp[8] __attribute__((aligned(16)));
    #pragma unroll
    for (int j = 0; j < 8; ++j) {
        int k = c * 32 + qq * 8 + j;
        tmp[j] = f2bf(W[k * 64 + t * 16 + m]);
    }
    *(bf16x8*)&out[F * 8] = *(const bf16x8*)tmp;
}

// --- edge kernel: MFMA pipeline -----------------------------------------
// block = 256 thr = 4 waves; 64 edges per group; wave w owns edges [w*16,w*16+16).
// LDS: sWf 40 KB frag-ordered weights; sInp [64][200] bf16 (inp rows, padded);
//      sM [64][72] bf16 (masked messages); geometry arrays. Total ~77.5 KB.

__global__ __launch_bounds__(256, 2)
void edge_kernel(const short* __restrict__ hbf, const float* __restrict__ x,
                 const int* __restrict__ edst, const int* __restrict__ esrc,
                 const float* __restrict__ means, const float* __restrict__ stds,
                 const short* __restrict__ wfrag,
                 const float* __restrict__ bm1, const float* __restrict__ bm2,
                 const float* __restrict__ Wa, const float* __restrict__ ba,
                 const float* __restrict__ bx1, const float* __restrict__ Wx2,
                 short* __restrict__ msg, float4* __restrict__ disp,
                 int E, int ngroups)
{
    __shared__ short sWf[2560 * 8];     // 40960 B
    __shared__ short sInp[64 * 200];    // 25600 B, row stride 200 (400 B)
    __shared__ short sM[64 * 72];       // 9216 B, row stride 72 (144 B)
    __shared__ float sGeo[256];         // [0:64) dirx | [64:128) diry | [128:192) dirz | [192:256) msk
    __shared__ float sDist[64];
    __shared__ float sMeans[64], sIstd[64];

    const int tid  = threadIdx.x;
    const int lane = tid & 63;
    const int wv   = tid >> 6;
    const int lnE  = lane & 15;
    const int q    = lane >> 4;
    const int ebase = wv * 16;

    // block-start staging
    {
        const bf16x8* src8 = (const bf16x8*)wfrag;
        bf16x8* dst8 = (bf16x8*)sWf;
        #pragma unroll
        for (int i = 0; i < 10; ++i) dst8[tid + i * 256] = src8[tid + i * 256];
        if (tid < 64) { sMeans[tid] = means[tid]; sIstd[tid] = 1.0f / stds[tid]; }
    }

    // hoisted per-lane constants (feature f = t*16 + q*4 + r)
    float bm1R[16], bm2R[16], bx1R[16], waR[16], wx2R[16];
    #pragma unroll
    for (int t = 0; t < 4; ++t)
        #pragma unroll
        for (int r = 0; r < 4; ++r) {
            int f = t * 16 + q * 4 + r;
            bm1R[t * 4 + r] = bm1[f];
            bm2R[t * 4 + r] = bm2[f];
            bx1R[t * 4 + r] = bx1[f];
            waR[t * 4 + r]  = Wa[f];
            wx2R[t * 4 + r] = Wx2[f];
        }
    const float ba_s = ba[0];

    const bf16x8* hb8  = (const bf16x8*)hbf;
    const bf16x8* sWfA = (const bf16x8*)sWf;
    bf16x8* msg8 = (bf16x8*)msg;

    for (int g = blockIdx.x; g < ngroups; g += gridDim.x) {
        const int gbase = g * 64;
        __syncthreads();   // protect LDS reuse across iterations

        // --- geometry (one thread per edge) ---
        if (tid < 64) {
            int eg = gbase + tid;
            bool valid = eg < E;
            if (!valid) eg = E - 1;
            int d = edst[eg], s = esrc[eg];
            float dx = x[d * 3 + 0] - x[s * 3 + 0];
            float dy = x[d * 3 + 1] - x[s * 3 + 1];
            float dz = x[d * 3 + 2] - x[s * 3 + 2];
            float dist = sqrtf(dx * dx + dy * dy + dz * dz);
            float inv = 1.0f / dist;
            sGeo[tid]       = dx * inv;
            sGeo[64 + tid]  = dy * inv;
            sGeo[128 + tid] = dz * inv;
            sGeo[192 + tid] = (valid && dist <= 3.0f) ? 1.0f : 0.0f;
            sDist[tid] = dist;
        }
        // --- gather h rows (16 B per thread-seg; 8 segs per 128-B row) ---
        #pragma unroll
        for (int i = 0; i < 4; ++i) {
            int s = tid + i * 256;           // 0..1023
            int row = s >> 3, off = s & 7;
            int er = row & 63;
            int eg = gbase + er; if (eg >= E) eg = E - 1;
            int node = (row < 64) ? edst[eg] : esrc[eg];
            bf16x8 v = hb8[node * 8 + off];
            *(bf16x8*)&sInp[er * 200 + (row >> 6) * 64 + off * 8] = v;
        }
        __syncthreads();
        // --- rbf: edge e = tid&63, gaussian block gb = tid>>6 ---
        {
            int e = tid & 63, gb = tid >> 6;
            float dist = sDist[e];
            short tmp[16] __attribute__((aligned(16)));
            #pragma unroll
            for (int j = 0; j < 16; ++j) {
                int gg = gb * 16 + j;
                float t = (dist - sMeans[gg]) * sIstd[gg];
                tmp[j] = f2bf(__expf(-0.5f * t * t));
            }
            *(bf16x8*)&sInp[e * 200 + 128 + gb * 16]     = *(const bf16x8*)&tmp[0];
            *(bf16x8*)&sInp[e * 200 + 128 + gb * 16 + 8] = *(const bf16x8*)&tmp[8];
        }
        __syncthreads();

        // --- per-wave MFMA pipeline on edges gbase+ebase .. +15 ---
        const int myrow = ebase + lnE;
        const bf16x8* inpB = (const bf16x8*)&sInp[myrow * 200];  // idx c*4+q

        // GEMM1: [16,192]@[192,64]
        f32x4 ac0 = {0,0,0,0}, ac1 = {0,0,0,0}, ac2 = {0,0,0,0}, ac3 = {0,0,0,0};
        #pragma unroll
        for (int c = 0; c < 6; ++c) {
            bf16x8 b = inpB[c * 4 + q];
            ac0 = __builtin_amdgcn_mfma_f32_16x16x32_bf16(sWfA[(c*4+0)*64 + lane], b, ac0, 0,0,0);
            ac1 = __builtin_amdgcn_mfma_f32_16x16x32_bf16(sWfA[(c*4+1)*64 + lane], b, ac1, 0,0,0);
            ac2 = __builtin_amdgcn_mfma_f32_16x16x32_bf16(sWfA[(c*4+2)*64 + lane], b, ac2, 0,0,0);
            ac3 = __builtin_amdgcn_mfma_f32_16x16x32_bf16(sWfA[(c*4+3)*64 + lane], b, ac3, 0,0,0);
        }
        // bias+silu -> m1 overlaid into this wave's inp rows (k = f positions)
        {
            f32x4 a[4] = {ac0, ac1, ac2, ac3};
            #pragma unroll
            for (int t = 0; t < 4; ++t) {
                short v4[4] __attribute__((aligned(8)));
                #pragma unroll
                for (int r = 0; r < 4; ++r)
                    v4[r] = f2bf(silu(a[t][r] + bm1R[t * 4 + r]));
                *(short4v*)&sInp[myrow * 200 + t * 16 + q * 4] = *(const short4v*)v4;
            }
        }
        // GEMM2: [16,64]@[64,64]
        f32x4 b0 = {0,0,0,0}, b1 = {0,0,0,0}, b2 = {0,0,0,0}, b3 = {0,0,0,0};
        #pragma unroll
        for (int c = 0; c < 2; ++c) {
            bf16x8 b = inpB[c * 4 + q];
            b0 = __builtin_amdgcn_mfma_f32_16x16x32_bf16(sWfA[1536 + (c*4+0)*64 + lane], b, b0, 0,0,0);
            b1 = __builtin_amdgcn_mfma_f32_16x16x32_bf16(sWfA[1536 + (c*4+1)*64 + lane], b, b1, 0,0,0);
            b2 = __builtin_amdgcn_mfma_f32_16x16x32_bf16(sWfA[1536 + (c*4+2)*64 + lane], b, b2, 0,0,0);
            b3 = __builtin_amdgcn_mfma_f32_16x16x32_bf16(sWfA[1536 + (c*4+3)*64 + lane], b, b3, 0,0,0);
        }
        // m2 = silu(+bm2); attention dot
        float m2v[16];
        float p = 0.0f;
        {
            f32x4 a[4] = {b0, b1, b2, b3};
            #pragma unroll
            for (int t = 0; t < 4; ++t)
                #pragma unroll
                for (int r = 0; r < 4; ++r) {
                    float v = silu(a[t][r] + bm2R[t * 4 + r]);
                    m2v[t * 4 + r] = v;
                    p += v * waR[t * 4 + r];
                }
        }
        p += __shfl_xor(p, 16, 64);
        p += __shfl_xor(p, 32, 64);
        const float att = sigm(p + ba_s);
        const float mskE = sGeo[192 + ebase + lnE];
        const float sc = att * mskE;
        // m -> sM (block-visible for msg store; wave-local for GEMM3 B)
        #pragma unroll
        for (int t = 0; t < 4; ++t) {
            short v4[4] __attribute__((aligned(8)));
            #pragma unroll
            for (int r = 0; r < 4; ++r)
                v4[r] = f2bf(m2v[t * 4 + r] * sc);
            *(short4v*)&sM[myrow * 72 + t * 16 + q * 4] = *(const short4v*)v4;
        }
        // GEMM3: [16,64]@[64,64] (x branch)
        const bf16x8* mB = (const bf16x8*)&sM[myrow * 72];  // idx c*4+q
        f32x4 c0 = {0,0,0,0}, c1 = {0,0,0,0}, c2 = {0,0,0,0}, c3 = {0,0,0,0};
        #pragma unroll
        for (int c = 0; c < 2; ++c) {
            bf16x8 b = mB[c * 4 + q];
            c0 = __builtin_amdgcn_mfma_f32_16x16x32_bf16(sWfA[2048 + (c*4+0)*64 + lane], b, c0, 0,0,0);
            c1 = __builtin_amdgcn_mfma_f32_16x16x32_bf16(sWfA[2048 + (c*4+1)*64 + lane], b, c1, 0,0,0);
            c2 = __builtin_amdgcn_mfma_f32_16x16x32_bf16(sWfA[2048 + (c*4+2)*64 + lane], b, c2, 0,0,0);
            c3 = __builtin_amdgcn_mfma_f32_16x16x32_bf16(sWfA[2048 + (c*4+3)*64 + lane], b, c3, 0,0,0);
        }
        float p3 = 0.0f;
        {
            f32x4 a[4] = {c0, c1, c2, c3};
            #pragma unroll
            for (int t = 0; t < 4; ++t)
                #pragma unroll
                for (int r = 0; r < 4; ++r)
                    p3 += silu(a[t][r] + bx1R[t * 4 + r]) * wx2R[t * 4 + r];
        }
        p3 += __shfl_xor(p3, 16, 64);
        p3 += __shfl_xor(p3, 32, 64);
        const float mag = tanhf(p3) * mskE;
        if (q == 0) {
            int eg = gbase + ebase + lnE;
            if (eg < E) {
                int ei = ebase + lnE;
                disp[eg] = make_float4(sGeo[ei] * mag, sGeo[64 + ei] * mag,
                                       sGeo[128 + ei] * mag, 0.0f);
            }
        }
        __syncthreads();
        // --- block-coalesced msg store (strip 72 -> 64 padding) ---
        #pragma unroll
        for (int i = 0; i < 2; ++i) {
            int s = tid + i * 256;        // 0..511
            int e = s >> 3, off = s & 7;
            int eg = gbase + e;
            if (eg < E)
                msg8[eg * 8 + off] = *(const bf16x8*)&sM[e * 72 + off * 8];
        }
    }
}

// --- node kernel: CSR gather + h MLP + x update (unchanged structure) ---

__global__ __launch_bounds__(512, 4)
void node_kernel(const float* __restrict__ h, const float* __restrict__ x,
                 const int* __restrict__ off, const int* __restrict__ csr,
                 const __hip_bfloat16* __restrict__ msg, const float4* __restrict__ disp,
                 const float* __restrict__ Wh1, const float* __restrict__ bh1,
                 const float* __restrict__ Wh2, const float* __restrict__ bh2,
                 float* __restrict__ hout, float* __restrict__ xout, int N)
{
    __shared__ float sW[128 * 64 + 64 * 64];
    float* sWh1 = sW;
    float* sWh2 = sW + 128 * 64;
    for (int i = threadIdx.x; i < 128 * 64; i += blockDim.x) sWh1[i] = Wh1[i];
    for (int i = threadIdx.x; i < 64 * 64;  i += blockDim.x) sWh2[i] = Wh2[i];
    __syncthreads();

    const int lane = threadIdx.x & 63;
    const int wid  = (blockIdx.x * blockDim.x + threadIdx.x) >> 6;
    if (wid >= N) return;

    const int row = off[wid];
    const int end = off[wid + 1];

    float accm = 0.0f;
    float dsum = 0.0f;
    for (int idx = row; idx < end; ++idx) {
        int eid = __builtin_amdgcn_readfirstlane(csr[idx]);
        accm += __bfloat162float(msg[(size_t)eid * 64 + lane]);
        if (lane < 3) {
            const float* dp = (const float*)&disp[eid];
            dsum += dp[lane];
        }
    }

    const float hn = h[(size_t)wid * 64 + lane];

    float acc = bh1[lane];
    #pragma unroll
    for (int k = 0; k < 64; ++k)
        acc = fmaf(rl(hn, k), sWh1[k * 64 + lane], acc);
    #pragma unroll
    for (int k = 0; k < 64; ++k)
        acc = fmaf(rl(accm, k), sWh1[(64 + k) * 64 + lane], acc);
    float t = silu(acc);

    float acc2 = bh2[lane];
    #pragma unroll
    for (int k = 0; k < 64; ++k)
        acc2 = fmaf(rl(t, k), sWh2[k * 64 + lane], acc2);

    hout[(size_t)wid * 64 + lane] = hn + acc2;
    if (lane < 3) xout[(size_t)wid * 3 + lane] = x[wid * 3 + lane] + dsum;
}

// --- launch --------------------------------------------------------------

extern "C" void kernel_launch(void* const* d_in, const int* in_sizes, int n_in,
                              void* d_out, int out_size, void* d_ws, size_t ws_size,
                              hipStream_t stream) {
    const float* h    = (const float*)d_in[0];
    const float* x    = (const float*)d_in[1];
    const int*   edst = (const int*)d_in[2];
    const int*   esrc = (const int*)d_in[3];
    const float* means= (const float*)d_in[4];
    const float* stds = (const float*)d_in[5];
    const float* Wm1  = (const float*)d_in[6];
    const float* bm1  = (const float*)d_in[7];
    const float* Wm2  = (const float*)d_in[8];
    const float* bm2  = (const float*)d_in[9];
    const float* Wa   = (const float*)d_in[10];
    const float* ba   = (const float*)d_in[11];
    const float* Wx1  = (const float*)d_in[12];
    const float* bx1  = (const float*)d_in[13];
    const float* Wx2  = (const float*)d_in[14];
    const float* Wh1  = (const float*)d_in[15];
    const float* bh1  = (const float*)d_in[16];
    const float* Wh2  = (const float*)d_in[17];
    const float* bh2  = (const float*)d_in[18];

    const int N = in_sizes[0] / 64;
    const int E = in_sizes[2];

    float* hout = (float*)d_out;
    float* xout = hout + (size_t)N * 64;

    // workspace layout
    uintptr_t wp = (uintptr_t)d_ws;
    int* counts = (int*)wp;                 wp += (size_t)N * 4;
    int* off    = (int*)wp;                 wp += (size_t)(N + 1) * 4;
    int* cursor = (int*)wp;                 wp += (size_t)N * 4;
    int* csr    = (int*)wp;                 wp += (size_t)E * 4;
    wp = (wp + 255) & ~(uintptr_t)255;
    short* msg  = (short*)wp;               wp += (size_t)E * 64 * 2;
    wp = (wp + 255) & ~(uintptr_t)255;
    float4* disp = (float4*)wp;             wp += (size_t)E * 16;
    wp = (wp + 255) & ~(uintptr_t)255;
    short* hbf  = (short*)wp;               wp += (size_t)N * 64 * 2;
    wp = (wp + 255) & ~(uintptr_t)255;
    short* wfrag = (short*)wp;              wp += 2560 * 8 * 2;

    // CSR build
    zero_kernel<<<(N + 255) / 256, 256, 0, stream>>>(counts, N);
    hist_kernel<<<(E + 255) / 256, 256, 0, stream>>>(edst, counts, E);
    scan_kernel<<<1, 1024, 0, stream>>>(counts, off, cursor, N);
    scatter_kernel<<<(E + 255) / 256, 256, 0, stream>>>(edst, cursor, csr, E);

    // prestage
    h2bf_kernel<<<(N * 64 + 255) / 256, 256, 0, stream>>>(h, hbf, N * 64);
    wfrag_kernel<<<10, 256, 0, stream>>>(Wm1, Wm2, Wx1, wfrag);

    // edge pipeline
    const int ngroups = (E + 63) / 64;
    edge_kernel<<<1024, 256, 0, stream>>>(hbf, x, edst, esrc, means, stds, wfrag,
                                          bm1, bm2, Wa, ba, bx1, Wx2,
                                          msg, disp, E, ngroups);

    // node update
    node_kernel<<<(N + 7) / 8, 512, 0, stream>>>(h, x, off, csr,
                                                 (const __hip_bfloat16*)msg, disp,
                                                 Wh1, bh1, Wh2, bh2, hout, xout, N);
}

// Round 4
// 472.874 us; speedup vs baseline: 16.2442x; 1.3099x over previous
//
#include <hip/hip_runtime.h>
#include <hip/hip_bf16.h>
#include <math.h>
#include <stdint.h>

typedef __attribute__((ext_vector_type(8))) short bf16x8;
typedef __attribute__((ext_vector_type(4))) short short4v;
typedef __attribute__((ext_vector_type(4))) float f32x4;

// --- helpers -------------------------------------------------------------

__device__ __forceinline__ short f2bf(float f) {
    __hip_bfloat16 b = __float2bfloat16(f);
    return *reinterpret_cast<short*>(&b);
}

__device__ __forceinline__ float bf2f(short s) {
    __hip_bfloat16 b = *reinterpret_cast<__hip_bfloat16*>(&s);
    return __bfloat162float(b);
}

__device__ __forceinline__ float sigm(float z) { return 1.0f / (1.0f + __expf(-z)); }
__device__ __forceinline__ float silu(float z) { return z * sigm(z); }

// --- CSR build ----------------------------------------------------------

__global__ void zero_kernel(int* __restrict__ counts, int N) {
    int i = blockIdx.x * blockDim.x + threadIdx.x;
    if (i < N) counts[i] = 0;
}

__global__ void hist_kernel(const int* __restrict__ edst, int* __restrict__ counts, int E) {
    int e = blockIdx.x * blockDim.x + threadIdx.x;
    if (e < E) atomicAdd(&counts[edst[e]], 1);
}

// 1024-thread single-block scan, wave-shuffle based (3 barriers per chunk)
__global__ void scan_kernel(const int* __restrict__ counts,
                            int* __restrict__ off, int* __restrict__ cursor, int N) {
    __shared__ int sWsum[16];
    __shared__ int carry_s;
    const int tid = threadIdx.x;
    const int lane = tid & 63, wv = tid >> 6;
    if (tid == 0) carry_s = 0;
    __syncthreads();
    for (int base = 0; base < N; base += 1024) {
        int i = base + tid;
        int v = (i < N) ? counts[i] : 0;
        int s = v;
        #pragma unroll
        for (int d = 1; d < 64; d <<= 1) {
            int t = __shfl_up(s, d, 64);
            if (lane >= d) s += t;
        }
        if (lane == 63) sWsum[wv] = s;
        __syncthreads();
        if (wv == 0) {
            int w = (lane < 16) ? sWsum[lane] : 0;
            #pragma unroll
            for (int d = 1; d < 16; d <<= 1) {
                int t = __shfl_up(w, d, 64);
                if (lane >= d) w += t;
            }
            if (lane < 16) sWsum[lane] = w;   // inclusive wave-sums scan
        }
        __syncthreads();
        int waveoff = (wv == 0) ? 0 : sWsum[wv - 1];
        int exc = carry_s + waveoff + s - v;
        if (i < N) { off[i] = exc; cursor[i] = exc; }
        int ctot = sWsum[15];
        __syncthreads();
        if (tid == 0) carry_s += ctot;
        __syncthreads();
    }
    if (tid == 0) off[N] = carry_s;
}

// assign each edge its slot in dst-bucketed order
__global__ void scatter_kernel(const int* __restrict__ edst,
                               int* __restrict__ cursor, int* __restrict__ eslot, int E) {
    int e = blockIdx.x * blockDim.x + threadIdx.x;
    if (e < E) {
        int d = edst[e];
        int p = atomicAdd(&cursor[d], 1);
        eslot[e] = p;
    }
}

// --- prestage: h -> bf16 -------------------------------------------------

__global__ void h2bf_kernel(const float* __restrict__ h, short* __restrict__ hb, int n) {
    int i = blockIdx.x * blockDim.x + threadIdx.x;
    if (i < n) hb[i] = f2bf(h[i]);
}

// --- prestage: weights -> MFMA A-fragment order (bf16) -------------------
// frag fi (within matrix): c = fi>>8, t=(fi>>6)&3, L=fi&63
//   element j: A[m=L&15][k] = W[(c*32 + (L>>4)*8 + j)*64 + t*16 + (L&15)]
// layout: Wm1 [0,1536) | Wm2 [1536,2048) | Wx1 [2048,2560) | Wh1 [2560,3584) | Wh2 [3584,4096)

__global__ void wfrag_kernel(const float* __restrict__ Wm1, const float* __restrict__ Wm2,
                             const float* __restrict__ Wx1, const float* __restrict__ Wh1,
                             const float* __restrict__ Wh2, short* __restrict__ out) {
    int F = blockIdx.x * blockDim.x + threadIdx.x;
    if (F >= 4096) return;
    const float* W; int fi;
    if (F < 1536)      { W = Wm1; fi = F; }
    else if (F < 2048) { W = Wm2; fi = F - 1536; }
    else if (F < 2560) { W = Wx1; fi = F - 2048; }
    else if (F < 3584) { W = Wh1; fi = F - 2560; }
    else               { W = Wh2; fi = F - 3584; }
    int c = fi >> 8;
    int t = (fi >> 6) & 3;
    int L = fi & 63;
    int m = L & 15, qq = L >> 4;
    short tmp[8] __attribute__((aligned(16)));
    #pragma unroll
    for (int j = 0; j < 8; ++j) {
        int k = c * 32 + qq * 8 + j;
        tmp[j] = f2bf(W[k * 64 + t * 16 + m]);
    }
    *(bf16x8*)&out[F * 8] = *(const bf16x8*)tmp;
}

// --- edge kernel: MFMA pipeline (stores at dst-bucketed slots) ----------

__global__ __launch_bounds__(256, 2)
void edge_kernel(const short* __restrict__ hbf, const float* __restrict__ x,
                 const int* __restrict__ edst, const int* __restrict__ esrc,
                 const int* __restrict__ eslot,
                 const float* __restrict__ means, const float* __restrict__ stds,
                 const short* __restrict__ wfrag,
                 const float* __restrict__ bm1, const float* __restrict__ bm2,
                 const float* __restrict__ Wa, const float* __restrict__ ba,
                 const float* __restrict__ bx1, const float* __restrict__ Wx2,
                 short* __restrict__ msg, float4* __restrict__ disp,
                 int E, int ngroups)
{
    __shared__ short sWf[2560 * 8];     // 40960 B
    __shared__ short sInp[64 * 200];    // 25600 B
    __shared__ short sM[64 * 72];       // 9216 B
    __shared__ float sGeo[256];
    __shared__ float sDist[64];
    __shared__ int   sSlot[64];
    __shared__ float sMeans[64], sIstd[64];

    const int tid  = threadIdx.x;
    const int lane = tid & 63;
    const int wv   = tid >> 6;
    const int lnE  = lane & 15;
    const int q    = lane >> 4;
    const int ebase = wv * 16;

    {
        const bf16x8* src8 = (const bf16x8*)wfrag;
        bf16x8* dst8 = (bf16x8*)sWf;
        #pragma unroll
        for (int i = 0; i < 10; ++i) dst8[tid + i * 256] = src8[tid + i * 256];
        if (tid < 64) { sMeans[tid] = means[tid]; sIstd[tid] = 1.0f / stds[tid]; }
    }

    float bm1R[16], bm2R[16], bx1R[16], waR[16], wx2R[16];
    #pragma unroll
    for (int t = 0; t < 4; ++t)
        #pragma unroll
        for (int r = 0; r < 4; ++r) {
            int f = t * 16 + q * 4 + r;
            bm1R[t * 4 + r] = bm1[f];
            bm2R[t * 4 + r] = bm2[f];
            bx1R[t * 4 + r] = bx1[f];
            waR[t * 4 + r]  = Wa[f];
            wx2R[t * 4 + r] = Wx2[f];
        }
    const float ba_s = ba[0];

    const bf16x8* hb8  = (const bf16x8*)hbf;
    const bf16x8* sWfA = (const bf16x8*)sWf;
    bf16x8* msg8 = (bf16x8*)msg;

    for (int g = blockIdx.x; g < ngroups; g += gridDim.x) {
        const int gbase = g * 64;
        __syncthreads();

        if (tid < 64) {
            int eg = gbase + tid;
            bool valid = eg < E;
            if (!valid) eg = E - 1;
            int d = edst[eg], s = esrc[eg];
            float dx = x[d * 3 + 0] - x[s * 3 + 0];
            float dy = x[d * 3 + 1] - x[s * 3 + 1];
            float dz = x[d * 3 + 2] - x[s * 3 + 2];
            float dist = sqrtf(dx * dx + dy * dy + dz * dz);
            float inv = 1.0f / dist;
            sGeo[tid]       = dx * inv;
            sGeo[64 + tid]  = dy * inv;
            sGeo[128 + tid] = dz * inv;
            sGeo[192 + tid] = (valid && dist <= 3.0f) ? 1.0f : 0.0f;
            sDist[tid] = dist;
            sSlot[tid] = eslot[eg];
        }
        #pragma unroll
        for (int i = 0; i < 4; ++i) {
            int s = tid + i * 256;
            int row = s >> 3, off = s & 7;
            int er = row & 63;
            int eg = gbase + er; if (eg >= E) eg = E - 1;
            int node = (row < 64) ? edst[eg] : esrc[eg];
            bf16x8 v = hb8[(size_t)node * 8 + off];
            *(bf16x8*)&sInp[er * 200 + (row >> 6) * 64 + off * 8] = v;
        }
        __syncthreads();
        {
            int e = tid & 63, gb = tid >> 6;
            float dist = sDist[e];
            short tmp[16] __attribute__((aligned(16)));
            #pragma unroll
            for (int j = 0; j < 16; ++j) {
                int gg = gb * 16 + j;
                float t = (dist - sMeans[gg]) * sIstd[gg];
                tmp[j] = f2bf(__expf(-0.5f * t * t));
            }
            *(bf16x8*)&sInp[e * 200 + 128 + gb * 16]     = *(const bf16x8*)&tmp[0];
            *(bf16x8*)&sInp[e * 200 + 128 + gb * 16 + 8] = *(const bf16x8*)&tmp[8];
        }
        __syncthreads();

        const int myrow = ebase + lnE;
        const bf16x8* inpB = (const bf16x8*)&sInp[myrow * 200];

        f32x4 ac0 = {0,0,0,0}, ac1 = {0,0,0,0}, ac2 = {0,0,0,0}, ac3 = {0,0,0,0};
        #pragma unroll
        for (int c = 0; c < 6; ++c) {
            bf16x8 b = inpB[c * 4 + q];
            ac0 = __builtin_amdgcn_mfma_f32_16x16x32_bf16(sWfA[(c*4+0)*64 + lane], b, ac0, 0,0,0);
            ac1 = __builtin_amdgcn_mfma_f32_16x16x32_bf16(sWfA[(c*4+1)*64 + lane], b, ac1, 0,0,0);
            ac2 = __builtin_amdgcn_mfma_f32_16x16x32_bf16(sWfA[(c*4+2)*64 + lane], b, ac2, 0,0,0);
            ac3 = __builtin_amdgcn_mfma_f32_16x16x32_bf16(sWfA[(c*4+3)*64 + lane], b, ac3, 0,0,0);
        }
        {
            f32x4 a[4] = {ac0, ac1, ac2, ac3};
            #pragma unroll
            for (int t = 0; t < 4; ++t) {
                short v4[4] __attribute__((aligned(8)));
                #pragma unroll
                for (int r = 0; r < 4; ++r)
                    v4[r] = f2bf(silu(a[t][r] + bm1R[t * 4 + r]));
                *(short4v*)&sInp[myrow * 200 + t * 16 + q * 4] = *(const short4v*)v4;
            }
        }
        f32x4 b0 = {0,0,0,0}, b1 = {0,0,0,0}, b2 = {0,0,0,0}, b3 = {0,0,0,0};
        #pragma unroll
        for (int c = 0; c < 2; ++c) {
            bf16x8 b = inpB[c * 4 + q];
            b0 = __builtin_amdgcn_mfma_f32_16x16x32_bf16(sWfA[1536 + (c*4+0)*64 + lane], b, b0, 0,0,0);
            b1 = __builtin_amdgcn_mfma_f32_16x16x32_bf16(sWfA[1536 + (c*4+1)*64 + lane], b, b1, 0,0,0);
            b2 = __builtin_amdgcn_mfma_f32_16x16x32_bf16(sWfA[1536 + (c*4+2)*64 + lane], b, b2, 0,0,0);
            b3 = __builtin_amdgcn_mfma_f32_16x16x32_bf16(sWfA[1536 + (c*4+3)*64 + lane], b, b3, 0,0,0);
        }
        float m2v[16];
        float p = 0.0f;
        {
            f32x4 a[4] = {b0, b1, b2, b3};
            #pragma unroll
            for (int t = 0; t < 4; ++t)
                #pragma unroll
                for (int r = 0; r < 4; ++r) {
                    float v = silu(a[t][r] + bm2R[t * 4 + r]);
                    m2v[t * 4 + r] = v;
                    p += v * waR[t * 4 + r];
                }
        }
        p += __shfl_xor(p, 16, 64);
        p += __shfl_xor(p, 32, 64);
        const float att = sigm(p + ba_s);
        const float mskE = sGeo[192 + ebase + lnE];
        const float sc = att * mskE;
        #pragma unroll
        for (int t = 0; t < 4; ++t) {
            short v4[4] __attribute__((aligned(8)));
            #pragma unroll
            for (int r = 0; r < 4; ++r)
                v4[r] = f2bf(m2v[t * 4 + r] * sc);
            *(short4v*)&sM[myrow * 72 + t * 16 + q * 4] = *(const short4v*)v4;
        }
        const bf16x8* mB = (const bf16x8*)&sM[myrow * 72];
        f32x4 c0 = {0,0,0,0}, c1 = {0,0,0,0}, c2 = {0,0,0,0}, c3 = {0,0,0,0};
        #pragma unroll
        for (int c = 0; c < 2; ++c) {
            bf16x8 b = mB[c * 4 + q];
            c0 = __builtin_amdgcn_mfma_f32_16x16x32_bf16(sWfA[2048 + (c*4+0)*64 + lane], b, c0, 0,0,0);
            c1 = __builtin_amdgcn_mfma_f32_16x16x32_bf16(sWfA[2048 + (c*4+1)*64 + lane], b, c1, 0,0,0);
            c2 = __builtin_amdgcn_mfma_f32_16x16x32_bf16(sWfA[2048 + (c*4+2)*64 + lane], b, c2, 0,0,0);
            c3 = __builtin_amdgcn_mfma_f32_16x16x32_bf16(sWfA[2048 + (c*4+3)*64 + lane], b, c3, 0,0,0);
        }
        float p3 = 0.0f;
        {
            f32x4 a[4] = {c0, c1, c2, c3};
            #pragma unroll
            for (int t = 0; t < 4; ++t)
                #pragma unroll
                for (int r = 0; r < 4; ++r)
                    p3 += silu(a[t][r] + bx1R[t * 4 + r]) * wx2R[t * 4 + r];
        }
        p3 += __shfl_xor(p3, 16, 64);
        p3 += __shfl_xor(p3, 32, 64);
        const float mag = tanhf(p3) * mskE;
        if (q == 0) {
            int eg = gbase + ebase + lnE;
            if (eg < E) {
                int ei = ebase + lnE;
                int slot = sSlot[ei];
                disp[slot] = make_float4(sGeo[ei] * mag, sGeo[64 + ei] * mag,
                                         sGeo[128 + ei] * mag, 0.0f);
            }
        }
        __syncthreads();
        #pragma unroll
        for (int i = 0; i < 2; ++i) {
            int s = tid + i * 256;
            int e = s >> 3, off = s & 7;
            int eg = gbase + e;
            if (eg < E) {
                int slot = sSlot[e];
                msg8[(size_t)slot * 8 + off] = *(const bf16x8*)&sM[e * 72 + off * 8];
            }
        }
    }
}

// --- node kernel: contiguous gather + MFMA MLP --------------------------
// block = 256 thr = 4 waves; 64 nodes per block; wave w owns rows [w*16, w*16+16).
// LDS: sWfN 24576 + sB 17408 + sOut 17408 + sXd 1024 = 60416 B -> 2 blocks/CU.

__global__ __launch_bounds__(256, 2)
void node_kernel(const short* __restrict__ hbf, const float* __restrict__ h,
                 const float* __restrict__ x, const int* __restrict__ off,
                 const short* __restrict__ msg, const float4* __restrict__ disp,
                 const short* __restrict__ wfragN,
                 const float* __restrict__ bh1, const float* __restrict__ bh2,
                 float* __restrict__ hout, float* __restrict__ xout, int N)
{
    __shared__ short sWfN[1536 * 8];    // Wh1 frags [0,1024) | Wh2 [1024,1536)
    __shared__ short sB[64 * 136];      // [h(0:64) | msg(64:128)] bf16, stride 136
    __shared__ float sOut[64 * 68];
    __shared__ float sXd[64 * 4];

    const int tid  = threadIdx.x;
    const int lane = tid & 63;
    const int wv   = tid >> 6;
    const int lnE  = lane & 15;
    const int q    = lane >> 4;

    {
        const bf16x8* src8 = (const bf16x8*)wfragN;
        bf16x8* dst8 = (bf16x8*)sWfN;
        #pragma unroll
        for (int i = 0; i < 6; ++i) dst8[tid + i * 256] = src8[tid + i * 256];
    }

    float bh1R[16], bh2R[16];
    #pragma unroll
    for (int t = 0; t < 4; ++t)
        #pragma unroll
        for (int r = 0; r < 4; ++r) {
            int f = t * 16 + q * 4 + r;
            bh1R[t * 4 + r] = bh1[f];
            bh2R[t * 4 + r] = bh2[f];
        }

    const int gbase = blockIdx.x * 64;
    const bf16x8* hb8 = (const bf16x8*)hbf;
    const bf16x8* sWfA = (const bf16x8*)sWfN;

    // --- stage h rows (nodes contiguous -> fully coalesced) ---
    #pragma unroll
    for (int i = 0; i < 2; ++i) {
        int s = tid + i * 256;            // 0..511 = 64 rows x 8 segs
        int row = s >> 3, seg = s & 7;
        int nc = gbase + row; if (nc >= N) nc = N - 1;
        bf16x8 v = hb8[(size_t)nc * 8 + seg];
        *(bf16x8*)&sB[row * 136 + seg * 8] = v;
    }

    // --- gather messages: wave w, rows w*16..w*16+15, contiguous slots ---
    for (int i = 0; i < 16; ++i) {
        int row = wv * 16 + i;
        int nc = gbase + row; if (nc >= N) nc = N - 1;
        int r0 = off[nc], r1 = off[nc + 1];
        float accm = 0.0f;
        int idx = r0;
        for (; idx + 4 <= r1; idx += 4) {
            float a0 = bf2f(msg[(size_t)(idx + 0) * 64 + lane]);
            float a1 = bf2f(msg[(size_t)(idx + 1) * 64 + lane]);
            float a2 = bf2f(msg[(size_t)(idx + 2) * 64 + lane]);
            float a3 = bf2f(msg[(size_t)(idx + 3) * 64 + lane]);
            accm += (a0 + a1) + (a2 + a3);
        }
        for (; idx < r1; ++idx)
            accm += bf2f(msg[(size_t)idx * 64 + lane]);
        sB[row * 136 + 64 + lane] = f2bf(accm);

        // displacement sum: lane-parallel over rows (coalesced float4)
        float dx = 0.0f, dy = 0.0f, dz = 0.0f;
        for (int j = r0 + lane; j < r1; j += 64) {
            float4 d4 = disp[j];
            dx += d4.x; dy += d4.y; dz += d4.z;
        }
        #pragma unroll
        for (int d = 32; d >= 1; d >>= 1) {
            dx += __shfl_xor(dx, d, 64);
            dy += __shfl_xor(dy, d, 64);
            dz += __shfl_xor(dz, d, 64);
        }
        if (lane == 0) {
            sXd[row * 4 + 0] = dx;
            sXd[row * 4 + 1] = dy;
            sXd[row * 4 + 2] = dz;
        }
    }
    __syncthreads();

    // --- MFMA MLP: wave w handles rows w*16 + lnE ---
    const int myrow = wv * 16 + lnE;
    const bf16x8* inpB = (const bf16x8*)&sB[myrow * 136];

    // GEMM1: [16,128]@[128,64]
    f32x4 a0 = {0,0,0,0}, a1 = {0,0,0,0}, a2 = {0,0,0,0}, a3 = {0,0,0,0};
    #pragma unroll
    for (int c = 0; c < 4; ++c) {
        bf16x8 b = inpB[c * 4 + q];
        a0 = __builtin_amdgcn_mfma_f32_16x16x32_bf16(sWfA[(c*4+0)*64 + lane], b, a0, 0,0,0);
        a1 = __builtin_amdgcn_mfma_f32_16x16x32_bf16(sWfA[(c*4+1)*64 + lane], b, a1, 0,0,0);
        a2 = __builtin_amdgcn_mfma_f32_16x16x32_bf16(sWfA[(c*4+2)*64 + lane], b, a2, 0,0,0);
        a3 = __builtin_amdgcn_mfma_f32_16x16x32_bf16(sWfA[(c*4+3)*64 + lane], b, a3, 0,0,0);
    }
    {
        f32x4 a[4] = {a0, a1, a2, a3};
        #pragma unroll
        for (int t = 0; t < 4; ++t) {
            short v4[4] __attribute__((aligned(8)));
            #pragma unroll
            for (int r = 0; r < 4; ++r)
                v4[r] = f2bf(silu(a[t][r] + bh1R[t * 4 + r]));
            *(short4v*)&sB[myrow * 136 + t * 16 + q * 4] = *(const short4v*)v4;
        }
    }
    // GEMM2: [16,64]@[64,64]
    f32x4 b0 = {0,0,0,0}, b1 = {0,0,0,0}, b2 = {0,0,0,0}, b3 = {0,0,0,0};
    #pragma unroll
    for (int c = 0; c < 2; ++c) {
        bf16x8 b = inpB[c * 4 + q];
        b0 = __builtin_amdgcn_mfma_f32_16x16x32_bf16(sWfA[1024 + (c*4+0)*64 + lane], b, b0, 0,0,0);
        b1 = __builtin_amdgcn_mfma_f32_16x16x32_bf16(sWfA[1024 + (c*4+1)*64 + lane], b, b1, 0,0,0);
        b2 = __builtin_amdgcn_mfma_f32_16x16x32_bf16(sWfA[1024 + (c*4+2)*64 + lane], b, b2, 0,0,0);
        b3 = __builtin_amdgcn_mfma_f32_16x16x32_bf16(sWfA[1024 + (c*4+3)*64 + lane], b, b3, 0,0,0);
    }
    {
        f32x4 a[4] = {b0, b1, b2, b3};
        #pragma unroll
        for (int t = 0; t < 4; ++t) {
            float v4[4] __attribute__((aligned(16)));
            #pragma unroll
            for (int r = 0; r < 4; ++r)
                v4[r] = a[t][r] + bh2R[t * 4 + r];
            *(f32x4*)&sOut[myrow * 68 + t * 16 + q * 4] = *(const f32x4*)v4;
        }
    }
    __syncthreads();

    // --- coalesced stores ---
    #pragma unroll
    for (int i = 0; i < 16; ++i) {
        int s = tid + i * 256;            // 0..4095
        int row = s >> 6, f = s & 63;
        int n = gbase + row;
        if (n < N)
            hout[(size_t)n * 64 + f] = h[(size_t)n * 64 + f] + sOut[row * 68 + f];
    }
    if (tid < 192) {
        int row = tid / 3, comp = tid % 3;
        int n = gbase + row;
        if (n < N)
            xout[(size_t)n * 3 + comp] = x[(size_t)n * 3 + comp] + sXd[row * 4 + comp];
    }
}

// --- launch --------------------------------------------------------------

extern "C" void kernel_launch(void* const* d_in, const int* in_sizes, int n_in,
                              void* d_out, int out_size, void* d_ws, size_t ws_size,
                              hipStream_t stream) {
    const float* h    = (const float*)d_in[0];
    const float* x    = (const float*)d_in[1];
    const int*   edst = (const int*)d_in[2];
    const int*   esrc = (const int*)d_in[3];
    const float* means= (const float*)d_in[4];
    const float* stds = (const float*)d_in[5];
    const float* Wm1  = (const float*)d_in[6];
    const float* bm1  = (const float*)d_in[7];
    const float* Wm2  = (const float*)d_in[8];
    const float* bm2  = (const float*)d_in[9];
    const float* Wa   = (const float*)d_in[10];
    const float* ba   = (const float*)d_in[11];
    const float* Wx1  = (const float*)d_in[12];
    const float* bx1  = (const float*)d_in[13];
    const float* Wx2  = (const float*)d_in[14];
    const float* Wh1  = (const float*)d_in[15];
    const float* bh1  = (const float*)d_in[16];
    const float* Wh2  = (const float*)d_in[17];
    const float* bh2  = (const float*)d_in[18];

    const int N = in_sizes[0] / 64;
    const int E = in_sizes[2];

    float* hout = (float*)d_out;
    float* xout = hout + (size_t)N * 64;

    // workspace layout
    uintptr_t wp = (uintptr_t)d_ws;
    int* counts = (int*)wp;                 wp += (size_t)N * 4;
    int* off    = (int*)wp;                 wp += (size_t)(N + 1) * 4;
    int* cursor = (int*)wp;                 wp += (size_t)N * 4;
    int* eslot  = (int*)wp;                 wp += (size_t)E * 4;
    wp = (wp + 255) & ~(uintptr_t)255;
    short* msg  = (short*)wp;               wp += (size_t)E * 64 * 2;
    wp = (wp + 255) & ~(uintptr_t)255;
    float4* disp = (float4*)wp;             wp += (size_t)E * 16;
    wp = (wp + 255) & ~(uintptr_t)255;
    short* hbf  = (short*)wp;               wp += (size_t)N * 64 * 2;
    wp = (wp + 255) & ~(uintptr_t)255;
    short* wfrag = (short*)wp;              wp += 4096 * 8 * 2;

    // CSR offsets + per-edge slots
    zero_kernel<<<(N + 255) / 256, 256, 0, stream>>>(counts, N);
    hist_kernel<<<(E + 255) / 256, 256, 0, stream>>>(edst, counts, E);
    scan_kernel<<<1, 1024, 0, stream>>>(counts, off, cursor, N);
    scatter_kernel<<<(E + 255) / 256, 256, 0, stream>>>(edst, cursor, eslot, E);

    // prestage
    h2bf_kernel<<<(N * 64 + 255) / 256, 256, 0, stream>>>(h, hbf, N * 64);
    wfrag_kernel<<<16, 256, 0, stream>>>(Wm1, Wm2, Wx1, Wh1, Wh2, wfrag);

    // edge pipeline
    const int ngroups = (E + 63) / 64;
    edge_kernel<<<1024, 256, 0, stream>>>(hbf, x, edst, esrc, eslot, means, stds, wfrag,
                                          bm1, bm2, Wa, ba, bx1, Wx2,
                                          msg, disp, E, ngroups);

    // node update
    node_kernel<<<(N + 63) / 64, 256, 0, stream>>>(hbf, h, x, off, msg, disp,
                                                   wfrag + 2560 * 8,
                                                   bh1, bh2, hout, xout, N);
}

// Round 5
// 435.753 us; speedup vs baseline: 17.6281x; 1.0852x over previous
//
#include <hip/hip_runtime.h>
#include <hip/hip_bf16.h>
#include <math.h>
#include <stdint.h>

typedef __attribute__((ext_vector_type(8))) short bf16x8;
typedef __attribute__((ext_vector_type(4))) short short4v;
typedef __attribute__((ext_vector_type(4))) float f32x4;

#if defined(__has_builtin)
#if __has_builtin(__builtin_amdgcn_cvt_pk_bf16_f32)
#define HAVE_PK_BF16 1
#endif
#endif

// --- helpers -------------------------------------------------------------

__device__ __forceinline__ short f2bf(float f) {
    __hip_bfloat16 b = __float2bfloat16(f);
    return *reinterpret_cast<short*>(&b);
}

__device__ __forceinline__ unsigned bfbits(float f) {
    unsigned u = __float_as_uint(f);
    return (u + 0x7fffu + ((u >> 16) & 1u)) >> 16;   // RNE (inputs are finite)
}

// pack two floats -> two bf16 in one dword
__device__ __forceinline__ unsigned pk2(float a, float b) {
#ifdef HAVE_PK_BF16
    typedef __attribute__((ext_vector_type(2))) __bf16 bf16v2;
    bf16v2 v = __builtin_amdgcn_cvt_pk_bf16_f32(a, b);
    unsigned u; __builtin_memcpy(&u, &v, 4);
    return u;
#else
    return bfbits(a) | (bfbits(b) << 16);
#endif
}

__device__ __forceinline__ float sigm(float z) { return 1.0f / (1.0f + __expf(-z)); }
__device__ __forceinline__ float silu(float z) { return z * sigm(z); }
__device__ __forceinline__ float tanh_fast(float x) {
    float e = __expf(2.0f * x);
    return 1.0f - 2.0f / (e + 1.0f);
}

// --- CSR build ----------------------------------------------------------

__global__ void zero_kernel(int* __restrict__ counts, int N) {
    int i = blockIdx.x * blockDim.x + threadIdx.x;
    if (i < N) counts[i] = 0;
}

__global__ void hist_kernel(const int* __restrict__ edst, int* __restrict__ counts, int E) {
    int e = blockIdx.x * blockDim.x + threadIdx.x;
    if (e < E) atomicAdd(&counts[edst[e]], 1);
}

// scan1: per-1024-block local exclusive scan + block sums
__global__ __launch_bounds__(1024)
void scan1_kernel(const int* __restrict__ counts, int* __restrict__ local,
                  int* __restrict__ bsum, int N) {
    __shared__ int sW[16];
    const int tid = threadIdx.x, lane = tid & 63, wv = tid >> 6;
    int i = blockIdx.x * 1024 + tid;
    int v = (i < N) ? counts[i] : 0;
    int s = v;
    #pragma unroll
    for (int d = 1; d < 64; d <<= 1) {
        int t = __shfl_up(s, d, 64);
        if (lane >= d) s += t;
    }
    if (lane == 63) sW[wv] = s;
    __syncthreads();
    if (wv == 0) {
        int w = (lane < 16) ? sW[lane] : 0;
        #pragma unroll
        for (int d = 1; d < 16; d <<= 1) {
            int t = __shfl_up(w, d, 64);
            if (lane >= d) w += t;
        }
        if (lane < 16) sW[lane] = w;   // inclusive wave-sum scan
    }
    __syncthreads();
    int waveoff = (wv == 0) ? 0 : sW[wv - 1];
    if (i < N) local[i] = waveoff + s - v;
    if (tid == 0) bsum[blockIdx.x] = sW[15];
}

// scan2: exclusive scan of block sums (nb <= 1024), single block
__global__ __launch_bounds__(1024)
void scan2_kernel(int* __restrict__ bsum, int nb) {
    __shared__ int sW[16];
    const int tid = threadIdx.x, lane = tid & 63, wv = tid >> 6;
    int v = (tid < nb) ? bsum[tid] : 0;
    int s = v;
    #pragma unroll
    for (int d = 1; d < 64; d <<= 1) {
        int t = __shfl_up(s, d, 64);
        if (lane >= d) s += t;
    }
    if (lane == 63) sW[wv] = s;
    __syncthreads();
    if (wv == 0) {
        int w = (lane < 16) ? sW[lane] : 0;
        #pragma unroll
        for (int d = 1; d < 16; d <<= 1) {
            int t = __shfl_up(w, d, 64);
            if (lane >= d) w += t;
        }
        if (lane < 16) sW[lane] = w;
    }
    __syncthreads();
    int waveoff = (wv == 0) ? 0 : sW[wv - 1];
    if (tid < nb) bsum[tid] = waveoff + s - v;
}

// scan3: off[i] = local[i] + bsum[i>>10]; cursor copy; off[N] = E
__global__ void scan3_kernel(const int* __restrict__ local, const int* __restrict__ bsum,
                             int* __restrict__ off, int* __restrict__ cursor,
                             int N, int E) {
    int i = blockIdx.x * blockDim.x + threadIdx.x;
    if (i < N) {
        int v = local[i] + bsum[i >> 10];
        off[i] = v;
        cursor[i] = v;
    }
    if (i == 0) off[N] = E;
}

// assign each edge its slot in dst-bucketed order
__global__ void scatter_kernel(const int* __restrict__ edst,
                               int* __restrict__ cursor, int* __restrict__ eslot, int E) {
    int e = blockIdx.x * blockDim.x + threadIdx.x;
    if (e < E) {
        int d = edst[e];
        int p = atomicAdd(&cursor[d], 1);
        eslot[e] = p;
    }
}

// --- prestage: h -> bf16 -------------------------------------------------

__global__ void h2bf_kernel(const float* __restrict__ h, short* __restrict__ hb, int n) {
    int i = blockIdx.x * blockDim.x + threadIdx.x;
    if (i < n) hb[i] = f2bf(h[i]);
}

// --- prestage: weights -> MFMA A-fragment order (bf16) -------------------
// layout: Wm1 [0,1536) | Wm2 [1536,2048) | Wx1 [2048,2560) | Wh1 [2560,3584) | Wh2 [3584,4096)

__global__ void wfrag_kernel(const float* __restrict__ Wm1, const float* __restrict__ Wm2,
                             const float* __restrict__ Wx1, const float* __restrict__ Wh1,
                             const float* __restrict__ Wh2, short* __restrict__ out) {
    int F = blockIdx.x * blockDim.x + threadIdx.x;
    if (F >= 4096) return;
    const float* W; int fi;
    if (F < 1536)      { W = Wm1; fi = F; }
    else if (F < 2048) { W = Wm2; fi = F - 1536; }
    else if (F < 2560) { W = Wx1; fi = F - 2048; }
    else if (F < 3584) { W = Wh1; fi = F - 2560; }
    else               { W = Wh2; fi = F - 3584; }
    int c = fi >> 8;
    int t = (fi >> 6) & 3;
    int L = fi & 63;
    int m = L & 15, qq = L >> 4;
    short tmp[8] __attribute__((aligned(16)));
    #pragma unroll
    for (int j = 0; j < 8; ++j) {
        int k = c * 32 + qq * 8 + j;
        tmp[j] = f2bf(W[k * 64 + t * 16 + m]);
    }
    *(bf16x8*)&out[F * 8] = *(const bf16x8*)tmp;
}

// --- edge kernel: MFMA pipeline (stores at dst-bucketed slots) ----------

__global__ __launch_bounds__(256, 2)
void edge_kernel(const short* __restrict__ hbf, const float* __restrict__ x,
                 const int* __restrict__ edst, const int* __restrict__ esrc,
                 const int* __restrict__ eslot,
                 const float* __restrict__ means, const float* __restrict__ stds,
                 const short* __restrict__ wfrag,
                 const float* __restrict__ bm1, const float* __restrict__ bm2,
                 const float* __restrict__ Wa, const float* __restrict__ ba,
                 const float* __restrict__ bx1, const float* __restrict__ Wx2,
                 short* __restrict__ msg, float4* __restrict__ disp,
                 int E, int ngroups)
{
    __shared__ short sWf[2560 * 8];     // 40960 B
    __shared__ short sInp[64 * 200];    // 25600 B
    __shared__ short sM[64 * 72];       // 9216 B
    __shared__ float sGeo[256];
    __shared__ float sDist[64];
    __shared__ int   sSlot[64];
    __shared__ float sMeans[64], sIstd[64];

    const int tid  = threadIdx.x;
    const int lane = tid & 63;
    const int wv   = tid >> 6;
    const int lnE  = lane & 15;
    const int q    = lane >> 4;
    const int ebase = wv * 16;

    {
        const bf16x8* src8 = (const bf16x8*)wfrag;
        bf16x8* dst8 = (bf16x8*)sWf;
        #pragma unroll
        for (int i = 0; i < 10; ++i) dst8[tid + i * 256] = src8[tid + i * 256];
        if (tid < 64) { sMeans[tid] = means[tid]; sIstd[tid] = 1.0f / stds[tid]; }
    }

    float bm1R[16], bm2R[16], bx1R[16], waR[16], wx2R[16];
    #pragma unroll
    for (int t = 0; t < 4; ++t)
        #pragma unroll
        for (int r = 0; r < 4; ++r) {
            int f = t * 16 + q * 4 + r;
            bm1R[t * 4 + r] = bm1[f];
            bm2R[t * 4 + r] = bm2[f];
            bx1R[t * 4 + r] = bx1[f];
            waR[t * 4 + r]  = Wa[f];
            wx2R[t * 4 + r] = Wx2[f];
        }
    const float ba_s = ba[0];

    const bf16x8* hb8  = (const bf16x8*)hbf;
    const bf16x8* sWfA = (const bf16x8*)sWf;
    bf16x8* msg8 = (bf16x8*)msg;

    for (int g = blockIdx.x; g < ngroups; g += gridDim.x) {
        const int gbase = g * 64;
        __syncthreads();

        if (tid < 64) {
            int eg = gbase + tid;
            bool valid = eg < E;
            if (!valid) eg = E - 1;
            int d = edst[eg], s = esrc[eg];
            float dx = x[d * 3 + 0] - x[s * 3 + 0];
            float dy = x[d * 3 + 1] - x[s * 3 + 1];
            float dz = x[d * 3 + 2] - x[s * 3 + 2];
            float dist = sqrtf(dx * dx + dy * dy + dz * dz);
            float inv = 1.0f / dist;
            sGeo[tid]       = dx * inv;
            sGeo[64 + tid]  = dy * inv;
            sGeo[128 + tid] = dz * inv;
            sGeo[192 + tid] = (valid && dist <= 3.0f) ? 1.0f : 0.0f;
            sDist[tid] = dist;
            sSlot[tid] = eslot[eg];
        }
        #pragma unroll
        for (int i = 0; i < 4; ++i) {
            int s = tid + i * 256;
            int row = s >> 3, off = s & 7;
            int er = row & 63;
            int eg = gbase + er; if (eg >= E) eg = E - 1;
            int node = (row < 64) ? edst[eg] : esrc[eg];
            bf16x8 v = hb8[(size_t)node * 8 + off];
            *(bf16x8*)&sInp[er * 200 + (row >> 6) * 64 + off * 8] = v;
        }
        __syncthreads();
        {
            int e = tid & 63, gb = tid >> 6;
            float dist = sDist[e];
            unsigned tmpu[4] __attribute__((aligned(16)));
            float ev[16];
            #pragma unroll
            for (int j = 0; j < 16; ++j) {
                int gg = gb * 16 + j;
                float t = (dist - sMeans[gg]) * sIstd[gg];
                ev[j] = __expf(-0.5f * t * t);
            }
            #pragma unroll
            for (int j = 0; j < 4; ++j)
                tmpu[j] = pk2(ev[2 * j], ev[2 * j + 1]);
            *(bf16x8*)&sInp[e * 200 + 128 + gb * 16] = *(const bf16x8*)tmpu;
            #pragma unroll
            for (int j = 0; j < 4; ++j)
                tmpu[j] = pk2(ev[8 + 2 * j], ev[8 + 2 * j + 1]);
            *(bf16x8*)&sInp[e * 200 + 128 + gb * 16 + 8] = *(const bf16x8*)tmpu;
        }
        __syncthreads();

        const int myrow = ebase + lnE;
        const bf16x8* inpB = (const bf16x8*)&sInp[myrow * 200];

        f32x4 ac0 = {0,0,0,0}, ac1 = {0,0,0,0}, ac2 = {0,0,0,0}, ac3 = {0,0,0,0};
        #pragma unroll
        for (int c = 0; c < 6; ++c) {
            bf16x8 b = inpB[c * 4 + q];
            ac0 = __builtin_amdgcn_mfma_f32_16x16x32_bf16(sWfA[(c*4+0)*64 + lane], b, ac0, 0,0,0);
            ac1 = __builtin_amdgcn_mfma_f32_16x16x32_bf16(sWfA[(c*4+1)*64 + lane], b, ac1, 0,0,0);
            ac2 = __builtin_amdgcn_mfma_f32_16x16x32_bf16(sWfA[(c*4+2)*64 + lane], b, ac2, 0,0,0);
            ac3 = __builtin_amdgcn_mfma_f32_16x16x32_bf16(sWfA[(c*4+3)*64 + lane], b, ac3, 0,0,0);
        }
        {
            f32x4 a[4] = {ac0, ac1, ac2, ac3};
            #pragma unroll
            for (int t = 0; t < 4; ++t) {
                uint2 st;
                st.x = pk2(silu(a[t][0] + bm1R[t * 4 + 0]), silu(a[t][1] + bm1R[t * 4 + 1]));
                st.y = pk2(silu(a[t][2] + bm1R[t * 4 + 2]), silu(a[t][3] + bm1R[t * 4 + 3]));
                *(uint2*)&sInp[myrow * 200 + t * 16 + q * 4] = st;
            }
        }
        f32x4 b0 = {0,0,0,0}, b1 = {0,0,0,0}, b2 = {0,0,0,0}, b3 = {0,0,0,0};
        #pragma unroll
        for (int c = 0; c < 2; ++c) {
            bf16x8 b = inpB[c * 4 + q];
            b0 = __builtin_amdgcn_mfma_f32_16x16x32_bf16(sWfA[1536 + (c*4+0)*64 + lane], b, b0, 0,0,0);
            b1 = __builtin_amdgcn_mfma_f32_16x16x32_bf16(sWfA[1536 + (c*4+1)*64 + lane], b, b1, 0,0,0);
            b2 = __builtin_amdgcn_mfma_f32_16x16x32_bf16(sWfA[1536 + (c*4+2)*64 + lane], b, b2, 0,0,0);
            b3 = __builtin_amdgcn_mfma_f32_16x16x32_bf16(sWfA[1536 + (c*4+3)*64 + lane], b, b3, 0,0,0);
        }
        float m2v[16];
        float p = 0.0f;
        {
            f32x4 a[4] = {b0, b1, b2, b3};
            #pragma unroll
            for (int t = 0; t < 4; ++t)
                #pragma unroll
                for (int r = 0; r < 4; ++r) {
                    float v = silu(a[t][r] + bm2R[t * 4 + r]);
                    m2v[t * 4 + r] = v;
                    p = fmaf(v, waR[t * 4 + r], p);
                }
        }
        p += __shfl_xor(p, 16, 64);
        p += __shfl_xor(p, 32, 64);
        const float att = sigm(p + ba_s);
        const float mskE = sGeo[192 + ebase + lnE];
        const float sc = att * mskE;
        #pragma unroll
        for (int t = 0; t < 4; ++t) {
            uint2 st;
            st.x = pk2(m2v[t * 4 + 0] * sc, m2v[t * 4 + 1] * sc);
            st.y = pk2(m2v[t * 4 + 2] * sc, m2v[t * 4 + 3] * sc);
            *(uint2*)&sM[myrow * 72 + t * 16 + q * 4] = st;
        }
        const bf16x8* mB = (const bf16x8*)&sM[myrow * 72];
        f32x4 c0 = {0,0,0,0}, c1 = {0,0,0,0}, c2 = {0,0,0,0}, c3 = {0,0,0,0};
        #pragma unroll
        for (int c = 0; c < 2; ++c) {
            bf16x8 b = mB[c * 4 + q];
            c0 = __builtin_amdgcn_mfma_f32_16x16x32_bf16(sWfA[2048 + (c*4+0)*64 + lane], b, c0, 0,0,0);
            c1 = __builtin_amdgcn_mfma_f32_16x16x32_bf16(sWfA[2048 + (c*4+1)*64 + lane], b, c1, 0,0,0);
            c2 = __builtin_amdgcn_mfma_f32_16x16x32_bf16(sWfA[2048 + (c*4+2)*64 + lane], b, c2, 0,0,0);
            c3 = __builtin_amdgcn_mfma_f32_16x16x32_bf16(sWfA[2048 + (c*4+3)*64 + lane], b, c3, 0,0,0);
        }
        float p3 = 0.0f;
        {
            f32x4 a[4] = {c0, c1, c2, c3};
            #pragma unroll
            for (int t = 0; t < 4; ++t)
                #pragma unroll
                for (int r = 0; r < 4; ++r)
                    p3 = fmaf(silu(a[t][r] + bx1R[t * 4 + r]), wx2R[t * 4 + r], p3);
        }
        p3 += __shfl_xor(p3, 16, 64);
        p3 += __shfl_xor(p3, 32, 64);
        const float mag = tanh_fast(p3) * mskE;
        if (q == 0) {
            int eg = gbase + ebase + lnE;
            if (eg < E) {
                int ei = ebase + lnE;
                int slot = sSlot[ei];
                disp[slot] = make_float4(sGeo[ei] * mag, sGeo[64 + ei] * mag,
                                         sGeo[128 + ei] * mag, 0.0f);
            }
        }
        __syncthreads();
        #pragma unroll
        for (int i = 0; i < 2; ++i) {
            int s = tid + i * 256;
            int e = s >> 3, off = s & 7;
            int eg = gbase + e;
            if (eg < E) {
                int slot = sSlot[e];
                msg8[(size_t)slot * 8 + off] = *(const bf16x8*)&sM[e * 72 + off * 8];
            }
        }
    }
}

// --- node kernel: contiguous gather (uint2, 4 rows/load) + MFMA MLP -----

__global__ __launch_bounds__(256, 2)
void node_kernel(const short* __restrict__ hbf, const float* __restrict__ h,
                 const float* __restrict__ x, const int* __restrict__ off,
                 const short* __restrict__ msg, const float4* __restrict__ disp,
                 const short* __restrict__ wfragN,
                 const float* __restrict__ bh1, const float* __restrict__ bh2,
                 float* __restrict__ hout, float* __restrict__ xout, int N)
{
    __shared__ short sWfN[1536 * 8];    // Wh1 frags [0,1024) | Wh2 [1024,1536)
    __shared__ short sB[64 * 136];      // [h(0:64) | msg(64:128)] bf16, stride 136
    __shared__ float sOut[64 * 68];
    __shared__ float sXd[64 * 4];

    const int tid  = threadIdx.x;
    const int lane = tid & 63;
    const int wv   = tid >> 6;
    const int lnE  = lane & 15;
    const int q    = lane >> 4;

    {
        const bf16x8* src8 = (const bf16x8*)wfragN;
        bf16x8* dst8 = (bf16x8*)sWfN;
        #pragma unroll
        for (int i = 0; i < 6; ++i) dst8[tid + i * 256] = src8[tid + i * 256];
    }

    float bh1R[16], bh2R[16];
    #pragma unroll
    for (int t = 0; t < 4; ++t)
        #pragma unroll
        for (int r = 0; r < 4; ++r) {
            int f = t * 16 + q * 4 + r;
            bh1R[t * 4 + r] = bh1[f];
            bh2R[t * 4 + r] = bh2[f];
        }

    const int gbase = blockIdx.x * 64;
    const bf16x8* hb8 = (const bf16x8*)hbf;
    const bf16x8* sWfA = (const bf16x8*)sWfN;
    const uint2* msg_u2 = (const uint2*)msg;

    // --- stage h rows (coalesced) ---
    #pragma unroll
    for (int i = 0; i < 2; ++i) {
        int s = tid + i * 256;
        int row = s >> 3, seg = s & 7;
        int nc = gbase + row; if (nc >= N) nc = N - 1;
        bf16x8 v = hb8[(size_t)nc * 8 + seg];
        *(bf16x8*)&sB[row * 136 + seg * 8] = v;
    }

    // --- gather messages: lane = (seg c, row-offset r); 4 rows per wave-load;
    //     2 nodes interleaved for 8 rows in flight ---
    const int c = lane & 15;
    const int r = lane >> 4;
    for (int i = 0; i < 16; i += 2) {
        int rowA = wv * 16 + i, rowB = rowA + 1;
        int nA = gbase + rowA; if (nA >= N) nA = N - 1;
        int nB = gbase + rowB; if (nB >= N) nB = N - 1;
        int a0 = off[nA], a1 = off[nA + 1];
        int b0 = off[nB], b1 = off[nB + 1];
        float accA[4] = {0,0,0,0}, accB[4] = {0,0,0,0};
        int ia = a0 + r, ib = b0 + r;
        while (ia < a1 || ib < b1) {
            if (ia < a1) {
                uint2 v = msg_u2[(size_t)ia * 16 + c];
                accA[0] += __uint_as_float(v.x << 16);
                accA[1] += __uint_as_float(v.x & 0xffff0000u);
                accA[2] += __uint_as_float(v.y << 16);
                accA[3] += __uint_as_float(v.y & 0xffff0000u);
            }
            if (ib < b1) {
                uint2 v = msg_u2[(size_t)ib * 16 + c];
                accB[0] += __uint_as_float(v.x << 16);
                accB[1] += __uint_as_float(v.x & 0xffff0000u);
                accB[2] += __uint_as_float(v.y << 16);
                accB[3] += __uint_as_float(v.y & 0xffff0000u);
            }
            ia += 4; ib += 4;
        }
        #pragma unroll
        for (int j = 0; j < 4; ++j) {
            accA[j] += __shfl_xor(accA[j], 16, 64);
            accA[j] += __shfl_xor(accA[j], 32, 64);
            accB[j] += __shfl_xor(accB[j], 16, 64);
            accB[j] += __shfl_xor(accB[j], 32, 64);
        }
        if (r == 0) {
            uint2 stA, stB;
            stA.x = pk2(accA[0], accA[1]); stA.y = pk2(accA[2], accA[3]);
            stB.x = pk2(accB[0], accB[1]); stB.y = pk2(accB[2], accB[3]);
            *(uint2*)&sB[rowA * 136 + 64 + c * 4] = stA;
            *(uint2*)&sB[rowB * 136 + 64 + c * 4] = stB;
        }
        // displacement sums (lane-parallel over slots)
        float dx = 0.0f, dy = 0.0f, dz = 0.0f;
        for (int j = a0 + lane; j < a1; j += 64) {
            float4 d4 = disp[j];
            dx += d4.x; dy += d4.y; dz += d4.z;
        }
        float ex = 0.0f, ey = 0.0f, ez = 0.0f;
        for (int j = b0 + lane; j < b1; j += 64) {
            float4 d4 = disp[j];
            ex += d4.x; ey += d4.y; ez += d4.z;
        }
        #pragma unroll
        for (int d = 32; d >= 1; d >>= 1) {
            dx += __shfl_xor(dx, d, 64);
            dy += __shfl_xor(dy, d, 64);
            dz += __shfl_xor(dz, d, 64);
            ex += __shfl_xor(ex, d, 64);
            ey += __shfl_xor(ey, d, 64);
            ez += __shfl_xor(ez, d, 64);
        }
        if (lane == 0) {
            sXd[rowA * 4 + 0] = dx; sXd[rowA * 4 + 1] = dy; sXd[rowA * 4 + 2] = dz;
            sXd[rowB * 4 + 0] = ex; sXd[rowB * 4 + 1] = ey; sXd[rowB * 4 + 2] = ez;
        }
    }
    __syncthreads();

    // --- MFMA MLP: wave w handles rows w*16 + lnE ---
    const int myrow = wv * 16 + lnE;
    const bf16x8* inpB = (const bf16x8*)&sB[myrow * 136];

    f32x4 a0 = {0,0,0,0}, a1 = {0,0,0,0}, a2 = {0,0,0,0}, a3 = {0,0,0,0};
    #pragma unroll
    for (int cc = 0; cc < 4; ++cc) {
        bf16x8 b = inpB[cc * 4 + q];
        a0 = __builtin_amdgcn_mfma_f32_16x16x32_bf16(sWfA[(cc*4+0)*64 + lane], b, a0, 0,0,0);
        a1 = __builtin_amdgcn_mfma_f32_16x16x32_bf16(sWfA[(cc*4+1)*64 + lane], b, a1, 0,0,0);
        a2 = __builtin_amdgcn_mfma_f32_16x16x32_bf16(sWfA[(cc*4+2)*64 + lane], b, a2, 0,0,0);
        a3 = __builtin_amdgcn_mfma_f32_16x16x32_bf16(sWfA[(cc*4+3)*64 + lane], b, a3, 0,0,0);
    }
    {
        f32x4 a[4] = {a0, a1, a2, a3};
        #pragma unroll
        for (int t = 0; t < 4; ++t) {
            uint2 st;
            st.x = pk2(silu(a[t][0] + bh1R[t * 4 + 0]), silu(a[t][1] + bh1R[t * 4 + 1]));
            st.y = pk2(silu(a[t][2] + bh1R[t * 4 + 2]), silu(a[t][3] + bh1R[t * 4 + 3]));
            *(uint2*)&sB[myrow * 136 + t * 16 + q * 4] = st;
        }
    }
    f32x4 b0 = {0,0,0,0}, b1 = {0,0,0,0}, b2 = {0,0,0,0}, b3 = {0,0,0,0};
    #pragma unroll
    for (int cc = 0; cc < 2; ++cc) {
        bf16x8 b = inpB[cc * 4 + q];
        b0 = __builtin_amdgcn_mfma_f32_16x16x32_bf16(sWfA[1024 + (cc*4+0)*64 + lane], b, b0, 0,0,0);
        b1 = __builtin_amdgcn_mfma_f32_16x16x32_bf16(sWfA[1024 + (cc*4+1)*64 + lane], b, b1, 0,0,0);
        b2 = __builtin_amdgcn_mfma_f32_16x16x32_bf16(sWfA[1024 + (cc*4+2)*64 + lane], b, b2, 0,0,0);
        b3 = __builtin_amdgcn_mfma_f32_16x16x32_bf16(sWfA[1024 + (cc*4+3)*64 + lane], b, b3, 0,0,0);
    }
    {
        f32x4 a[4] = {b0, b1, b2, b3};
        #pragma unroll
        for (int t = 0; t < 4; ++t) {
            float v4[4] __attribute__((aligned(16)));
            #pragma unroll
            for (int r2 = 0; r2 < 4; ++r2)
                v4[r2] = a[t][r2] + bh2R[t * 4 + r2];
            *(f32x4*)&sOut[myrow * 68 + t * 16 + q * 4] = *(const f32x4*)v4;
        }
    }
    __syncthreads();

    // --- coalesced stores ---
    #pragma unroll
    for (int i = 0; i < 16; ++i) {
        int s = tid + i * 256;
        int row = s >> 6, f = s & 63;
        int n = gbase + row;
        if (n < N)
            hout[(size_t)n * 64 + f] = h[(size_t)n * 64 + f] + sOut[row * 68 + f];
    }
    if (tid < 192) {
        int row = tid / 3, comp = tid % 3;
        int n = gbase + row;
        if (n < N)
            xout[(size_t)n * 3 + comp] = x[(size_t)n * 3 + comp] + sXd[row * 4 + comp];
    }
}

// --- launch --------------------------------------------------------------

extern "C" void kernel_launch(void* const* d_in, const int* in_sizes, int n_in,
                              void* d_out, int out_size, void* d_ws, size_t ws_size,
                              hipStream_t stream) {
    const float* h    = (const float*)d_in[0];
    const float* x    = (const float*)d_in[1];
    const int*   edst = (const int*)d_in[2];
    const int*   esrc = (const int*)d_in[3];
    const float* means= (const float*)d_in[4];
    const float* stds = (const float*)d_in[5];
    const float* Wm1  = (const float*)d_in[6];
    const float* bm1  = (const float*)d_in[7];
    const float* Wm2  = (const float*)d_in[8];
    const float* bm2  = (const float*)d_in[9];
    const float* Wa   = (const float*)d_in[10];
    const float* ba   = (const float*)d_in[11];
    const float* Wx1  = (const float*)d_in[12];
    const float* bx1  = (const float*)d_in[13];
    const float* Wx2  = (const float*)d_in[14];
    const float* Wh1  = (const float*)d_in[15];
    const float* bh1  = (const float*)d_in[16];
    const float* Wh2  = (const float*)d_in[17];
    const float* bh2  = (const float*)d_in[18];

    const int N = in_sizes[0] / 64;
    const int E = in_sizes[2];
    const int nb = (N + 1023) / 1024;

    float* hout = (float*)d_out;
    float* xout = hout + (size_t)N * 64;

    // workspace layout
    uintptr_t wp = (uintptr_t)d_ws;
    int* counts = (int*)wp;                 wp += (size_t)N * 4;
    int* off    = (int*)wp;                 wp += (size_t)(N + 1) * 4;
    int* cursor = (int*)wp;                 wp += (size_t)N * 4;
    int* local  = (int*)wp;                 wp += (size_t)N * 4;
    int* bsum   = (int*)wp;                 wp += 1024 * 4;
    int* eslot  = (int*)wp;                 wp += (size_t)E * 4;
    wp = (wp + 255) & ~(uintptr_t)255;
    short* msg  = (short*)wp;               wp += (size_t)E * 64 * 2;
    wp = (wp + 255) & ~(uintptr_t)255;
    float4* disp = (float4*)wp;             wp += (size_t)E * 16;
    wp = (wp + 255) & ~(uintptr_t)255;
    short* hbf  = (short*)wp;               wp += (size_t)N * 64 * 2;
    wp = (wp + 255) & ~(uintptr_t)255;
    short* wfrag = (short*)wp;              wp += 4096 * 8 * 2;

    // CSR offsets + per-edge slots (hierarchical scan)
    zero_kernel<<<(N + 255) / 256, 256, 0, stream>>>(counts, N);
    hist_kernel<<<(E + 255) / 256, 256, 0, stream>>>(edst, counts, E);
    scan1_kernel<<<nb, 1024, 0, stream>>>(counts, local, bsum, N);
    scan2_kernel<<<1, 1024, 0, stream>>>(bsum, nb);
    scan3_kernel<<<(N + 255) / 256, 256, 0, stream>>>(local, bsum, off, cursor, N, E);
    scatter_kernel<<<(E + 255) / 256, 256, 0, stream>>>(edst, cursor, eslot, E);

    // prestage
    h2bf_kernel<<<(N * 64 + 255) / 256, 256, 0, stream>>>(h, hbf, N * 64);
    wfrag_kernel<<<16, 256, 0, stream>>>(Wm1, Wm2, Wx1, Wh1, Wh2, wfrag);

    // edge pipeline
    const int ngroups = (E + 63) / 64;
    edge_kernel<<<1024, 256, 0, stream>>>(hbf, x, edst, esrc, eslot, means, stds, wfrag,
                                          bm1, bm2, Wa, ba, bx1, Wx2,
                                          msg, disp, E, ngroups);

    // node update
    node_kernel<<<(N + 63) / 64, 256, 0, stream>>>(hbf, h, x, off, msg, disp,
                                                   wfrag + 2560 * 8,
                                                   bh1, bh2, hout, xout, N);
}

// Round 6
// 410.584 us; speedup vs baseline: 18.7087x; 1.0613x over previous
//
#include <hip/hip_runtime.h>
#include <hip/hip_bf16.h>
#include <math.h>
#include <stdint.h>

typedef __attribute__((ext_vector_type(8))) short bf16x8;
typedef __attribute__((ext_vector_type(4))) float f32x4;

#if defined(__has_builtin)
#if __has_builtin(__builtin_amdgcn_cvt_pk_bf16_f32)
#define HAVE_PK_BF16 1
#endif
#endif

// --- helpers -------------------------------------------------------------

__device__ __forceinline__ short f2bf(float f) {
    __hip_bfloat16 b = __float2bfloat16(f);
    return *reinterpret_cast<short*>(&b);
}

__device__ __forceinline__ unsigned bfbits(float f) {
    unsigned u = __float_as_uint(f);
    return (u + 0x7fffu + ((u >> 16) & 1u)) >> 16;
}

__device__ __forceinline__ unsigned pk2(float a, float b) {
#ifdef HAVE_PK_BF16
    typedef __attribute__((ext_vector_type(2))) __bf16 bf16v2;
    bf16v2 v = __builtin_amdgcn_cvt_pk_bf16_f32(a, b);
    unsigned u; __builtin_memcpy(&u, &v, 4);
    return u;
#else
    return bfbits(a) | (bfbits(b) << 16);
#endif
}

__device__ __forceinline__ float sigm(float z) { return 1.0f / (1.0f + __expf(-z)); }
__device__ __forceinline__ float silu(float z) { return z * sigm(z); }
__device__ __forceinline__ float tanh_fast(float x) {
    float e = __expf(2.0f * x);
    return 1.0f - 2.0f / (e + 1.0f);
}

// --- CSR build ----------------------------------------------------------

__global__ void hist_kernel(const int* __restrict__ edst, int* __restrict__ counts, int E) {
    int e = blockIdx.x * blockDim.x + threadIdx.x;
    if (e < E) atomicAdd(&counts[edst[e]], 1);
}

__global__ __launch_bounds__(1024)
void scan1_kernel(const int* __restrict__ counts, int* __restrict__ local,
                  int* __restrict__ bsum, int N) {
    __shared__ int sW[16];
    const int tid = threadIdx.x, lane = tid & 63, wv = tid >> 6;
    int i = blockIdx.x * 1024 + tid;
    int v = (i < N) ? counts[i] : 0;
    int s = v;
    #pragma unroll
    for (int d = 1; d < 64; d <<= 1) {
        int t = __shfl_up(s, d, 64);
        if (lane >= d) s += t;
    }
    if (lane == 63) sW[wv] = s;
    __syncthreads();
    if (wv == 0) {
        int w = (lane < 16) ? sW[lane] : 0;
        #pragma unroll
        for (int d = 1; d < 16; d <<= 1) {
            int t = __shfl_up(w, d, 64);
            if (lane >= d) w += t;
        }
        if (lane < 16) sW[lane] = w;
    }
    __syncthreads();
    int waveoff = (wv == 0) ? 0 : sW[wv - 1];
    if (i < N) local[i] = waveoff + s - v;
    if (tid == 0) bsum[blockIdx.x] = sW[15];
}

__global__ __launch_bounds__(1024)
void scan2_kernel(int* __restrict__ bsum, int nb) {
    __shared__ int sW[16];
    const int tid = threadIdx.x, lane = tid & 63, wv = tid >> 6;
    int v = (tid < nb) ? bsum[tid] : 0;
    int s = v;
    #pragma unroll
    for (int d = 1; d < 64; d <<= 1) {
        int t = __shfl_up(s, d, 64);
        if (lane >= d) s += t;
    }
    if (lane == 63) sW[wv] = s;
    __syncthreads();
    if (wv == 0) {
        int w = (lane < 16) ? sW[lane] : 0;
        #pragma unroll
        for (int d = 1; d < 16; d <<= 1) {
            int t = __shfl_up(w, d, 64);
            if (lane >= d) w += t;
        }
        if (lane < 16) sW[lane] = w;
    }
    __syncthreads();
    int waveoff = (wv == 0) ? 0 : sW[wv - 1];
    if (tid < nb) bsum[tid] = waveoff + s - v;
}

__global__ void scan3_kernel(const int* __restrict__ local, const int* __restrict__ bsum,
                             int* __restrict__ off, int* __restrict__ cursor,
                             int N, int E) {
    int i = blockIdx.x * blockDim.x + threadIdx.x;
    if (i < N) {
        int v = local[i] + bsum[i >> 10];
        off[i] = v;
        cursor[i] = v;
    }
    if (i == 0) off[N] = E;
}

__global__ void scatter_kernel(const int* __restrict__ edst,
                               int* __restrict__ cursor, int* __restrict__ eslot, int E) {
    int e = blockIdx.x * blockDim.x + threadIdx.x;
    if (e < E) {
        int d = edst[e];
        int p = atomicAdd(&cursor[d], 1);
        eslot[e] = p;
    }
}

// --- prestage ------------------------------------------------------------

__global__ void h2bf_kernel(const float* __restrict__ h, short* __restrict__ hb, int n) {
    int i = blockIdx.x * blockDim.x + threadIdx.x;
    if (i < n) hb[i] = f2bf(h[i]);
}

// weights -> MFMA A-fragment order (bf16)
// layout: Wm1 [0,1536) | Wm2 [1536,2048) | Wx1 [2048,2560) | Wh1 [2560,3584) | Wh2 [3584,4096)
__global__ void wfrag_kernel(const float* __restrict__ Wm1, const float* __restrict__ Wm2,
                             const float* __restrict__ Wx1, const float* __restrict__ Wh1,
                             const float* __restrict__ Wh2, short* __restrict__ out) {
    int F = blockIdx.x * blockDim.x + threadIdx.x;
    if (F >= 4096) return;
    const float* W; int fi;
    if (F < 1536)      { W = Wm1; fi = F; }
    else if (F < 2048) { W = Wm2; fi = F - 1536; }
    else if (F < 2560) { W = Wx1; fi = F - 2048; }
    else if (F < 3584) { W = Wh1; fi = F - 2560; }
    else               { W = Wh2; fi = F - 3584; }
    int c = fi >> 8;
    int t = (fi >> 6) & 3;
    int L = fi & 63;
    int m = L & 15, qq = L >> 4;
    short tmp[8] __attribute__((aligned(16)));
    #pragma unroll
    for (int j = 0; j < 8; ++j) {
        int k = c * 32 + qq * 8 + j;
        tmp[j] = f2bf(W[k * 64 + t * 16 + m]);
    }
    *(bf16x8*)&out[F * 8] = *(const bf16x8*)tmp;
}

// --- edge kernel: pipelined MFMA, XOR-swizzled LDS ----------------------
// 256 thr / 4 waves; 64 edges/group. sInp: 64 rows x 256 shorts (32 16B-blocks),
// physical block = logical ^ (row & 7). Logical: 0..7 h_dst (m1 overlay),
// 8..15 h_src (m overlay), 16..23 rbf. 2-deep prefetch pipeline.

__global__ __launch_bounds__(256, 2)
void edge_kernel(const short* __restrict__ hbf, const float* __restrict__ x,
                 const int* __restrict__ edst, const int* __restrict__ esrc,
                 const int* __restrict__ eslot,
                 const float* __restrict__ means, const float* __restrict__ stds,
                 const short* __restrict__ wfrag,
                 const float* __restrict__ bm1, const float* __restrict__ bm2,
                 const float* __restrict__ Wa, const float* __restrict__ ba,
                 const float* __restrict__ bx1, const float* __restrict__ Wx2,
                 short* __restrict__ msg, float4* __restrict__ disp,
                 int E, int ngroups)
{
    __shared__ short sWf[2560 * 8];     // 40960 B
    __shared__ short sInp[64 * 256];    // 32768 B
    __shared__ float sGeo[256];         // dirx|diry|dirz|mask
    __shared__ int   sSlot[64];
    __shared__ float sMeans[64], sIstd[64];
    __shared__ float sBias[5 * 64];     // bm1|bm2|bx1|Wa|Wx2

    const int tid  = threadIdx.x;
    const int lane = tid & 63;
    const int wv   = tid >> 6;
    const int lnE  = lane & 15;
    const int q    = lane >> 4;
    const int ebase = wv * 16;
    const int seg  = tid & 7;

    // staging row constants
    int serow[4], sblkv[4];
    bool isDst[4];
    #pragma unroll
    for (int i = 0; i < 4; ++i) {
        int s = tid + i * 256;
        int row = s >> 3;
        serow[i] = row & 63;
        sblkv[i] = ((row >> 6) * 8 + seg) ^ (serow[i] & 7);
        isDst[i] = (row < 64);
    }

    {
        const bf16x8* src8 = (const bf16x8*)wfrag;
        bf16x8* dst8 = (bf16x8*)sWf;
        #pragma unroll
        for (int i = 0; i < 10; ++i) dst8[tid + i * 256] = src8[tid + i * 256];
        if (tid < 64) {
            sMeans[tid] = means[tid];
            sIstd[tid]  = 1.0f / stds[tid];
            sBias[tid]        = bm1[tid];
            sBias[64 + tid]   = bm2[tid];
            sBias[128 + tid]  = bx1[tid];
            sBias[192 + tid]  = Wa[tid];
            sBias[256 + tid]  = Wx2[tid];
        }
    }
    const float ba_s = ba[0];

    const bf16x8* hb8  = (const bf16x8*)hbf;
    const bf16x8* sWfA = (const bf16x8*)sWf;
    bf16x8* msg8 = (bf16x8*)msg;
    const int gstep = gridDim.x;

    auto ldIdx = [&](int gg, int ni[4], int& dN, int& sN) {
        int gc = gg < ngroups ? gg : ngroups - 1;
        int gb = gc * 64;
        #pragma unroll
        for (int i = 0; i < 4; ++i) {
            int eg = gb + serow[i]; if (eg >= E) eg = E - 1;
            ni[i] = isDst[i] ? edst[eg] : esrc[eg];
        }
        int eg2 = gb + lane; if (eg2 >= E) eg2 = E - 1;
        dN = edst[eg2]; sN = esrc[eg2];
    };
    auto ldPay = [&](int gg, const int ni[4], int dN, int sN,
                     bf16x8 hv[4], float xd[3], float xs[3], int& slot) {
        #pragma unroll
        for (int i = 0; i < 4; ++i) hv[i] = hb8[(size_t)ni[i] * 8 + seg];
        xd[0] = x[dN * 3 + 0]; xd[1] = x[dN * 3 + 1]; xd[2] = x[dN * 3 + 2];
        xs[0] = x[sN * 3 + 0]; xs[1] = x[sN * 3 + 1]; xs[2] = x[sN * 3 + 2];
        int gc = gg < ngroups ? gg : ngroups - 1;
        int eg2 = gc * 64 + lane; if (eg2 >= E) eg2 = E - 1;
        slot = eslot[eg2];
    };

    int g = blockIdx.x;
    if (g >= ngroups) return;

    int niA[4], dA, sA, slotA;
    bf16x8 hvA[4];
    float xdA[3], xsA[3];
    int niB[4], dB, sB2;
    ldIdx(g, niA, dA, sA);
    ldPay(g, niA, dA, sA, hvA, xdA, xsA, slotA);
    ldIdx(g + gstep, niB, dB, sB2);

    for (; g < ngroups; g += gstep) {
        const int gbase = g * 64;
        __syncthreads();   // LDS free (prev group's stores done)

        // ---- stage group g from registers ----
        #pragma unroll
        for (int i = 0; i < 4; ++i)
            *(bf16x8*)&sInp[serow[i] * 256 + sblkv[i] * 8] = hvA[i];

        float dx = xdA[0] - xsA[0], dy = xdA[1] - xsA[1], dz = xdA[2] - xsA[2];
        float dist = sqrtf(dx * dx + dy * dy + dz * dz);
        float inv = 1.0f / dist;
        float msk = (dist <= 3.0f) ? 1.0f : 0.0f;
        if (tid < 64) {
            sGeo[tid] = dx * inv; sGeo[64 + tid] = dy * inv; sGeo[128 + tid] = dz * inv;
            sGeo[192 + tid] = msk;
            sSlot[tid] = slotA;
        }
        {
            float ev[16];
            #pragma unroll
            for (int j = 0; j < 16; ++j) {
                int gg2 = wv * 16 + j;
                float t = (dist - sMeans[gg2]) * sIstd[gg2];
                ev[j] = __expf(-0.5f * t * t);
            }
            unsigned tu[4] __attribute__((aligned(16)));
            #pragma unroll
            for (int j2 = 0; j2 < 4; ++j2) tu[j2] = pk2(ev[2 * j2], ev[2 * j2 + 1]);
            int p0 = (16 + 2 * wv) ^ (lane & 7);
            *(bf16x8*)&sInp[lane * 256 + p0 * 8] = *(const bf16x8*)tu;
            #pragma unroll
            for (int j2 = 0; j2 < 4; ++j2) tu[j2] = pk2(ev[8 + 2 * j2], ev[9 + 2 * j2]);
            int p1 = (17 + 2 * wv) ^ (lane & 7);
            *(bf16x8*)&sInp[lane * 256 + p1 * 8] = *(const bf16x8*)tu;
        }

        // ---- prefetch next group (loads fly during compute) ----
        bf16x8 hvB[4]; float xdB[3], xsB[3]; int slotB;
        ldPay(g + gstep, niB, dB, sB2, hvB, xdB, xsB, slotB);
        int niC[4], dC, sC;
        ldIdx(g + 2 * gstep, niC, dC, sC);

        __syncthreads();

        // ---- compute ----
        const int myrow = ebase + lnE;
        const int sw = myrow & 7;
        short* inpRow = &sInp[myrow * 256];

        f32x4 ac0 = {0,0,0,0}, ac1 = {0,0,0,0}, ac2 = {0,0,0,0}, ac3 = {0,0,0,0};
        #pragma unroll
        for (int c = 0; c < 6; ++c) {
            bf16x8 b = *(const bf16x8*)&inpRow[(((c << 2) + q) ^ sw) * 8];
            ac0 = __builtin_amdgcn_mfma_f32_16x16x32_bf16(sWfA[(c*4+0)*64 + lane], b, ac0, 0,0,0);
            ac1 = __builtin_amdgcn_mfma_f32_16x16x32_bf16(sWfA[(c*4+1)*64 + lane], b, ac1, 0,0,0);
            ac2 = __builtin_amdgcn_mfma_f32_16x16x32_bf16(sWfA[(c*4+2)*64 + lane], b, ac2, 0,0,0);
            ac3 = __builtin_amdgcn_mfma_f32_16x16x32_bf16(sWfA[(c*4+3)*64 + lane], b, ac3, 0,0,0);
        }
        {
            f32x4 a[4] = {ac0, ac1, ac2, ac3};
            #pragma unroll
            for (int t = 0; t < 4; ++t) {
                int fb = t * 16 + q * 4;
                uint2 st;
                st.x = pk2(silu(a[t][0] + sBias[fb + 0]), silu(a[t][1] + sBias[fb + 1]));
                st.y = pk2(silu(a[t][2] + sBias[fb + 2]), silu(a[t][3] + sBias[fb + 3]));
                int phys = ((t << 1) + (q >> 1)) ^ sw;
                *(uint2*)&inpRow[phys * 8 + (q & 1) * 4] = st;
            }
        }
        f32x4 b0 = {0,0,0,0}, b1 = {0,0,0,0}, b2 = {0,0,0,0}, b3 = {0,0,0,0};
        #pragma unroll
        for (int c = 0; c < 2; ++c) {
            bf16x8 b = *(const bf16x8*)&inpRow[(((c << 2) + q) ^ sw) * 8];
            b0 = __builtin_amdgcn_mfma_f32_16x16x32_bf16(sWfA[1536 + (c*4+0)*64 + lane], b, b0, 0,0,0);
            b1 = __builtin_amdgcn_mfma_f32_16x16x32_bf16(sWfA[1536 + (c*4+1)*64 + lane], b, b1, 0,0,0);
            b2 = __builtin_amdgcn_mfma_f32_16x16x32_bf16(sWfA[1536 + (c*4+2)*64 + lane], b, b2, 0,0,0);
            b3 = __builtin_amdgcn_mfma_f32_16x16x32_bf16(sWfA[1536 + (c*4+3)*64 + lane], b, b3, 0,0,0);
        }
        float m2v[16];
        float p = 0.0f;
        {
            f32x4 a[4] = {b0, b1, b2, b3};
            #pragma unroll
            for (int t = 0; t < 4; ++t)
                #pragma unroll
                for (int r = 0; r < 4; ++r) {
                    int f = t * 16 + q * 4 + r;
                    float v = silu(a[t][r] + sBias[64 + f]);
                    m2v[t * 4 + r] = v;
                    p = fmaf(v, sBias[192 + f], p);
                }
        }
        p += __shfl_xor(p, 16, 64);
        p += __shfl_xor(p, 32, 64);
        const float att = sigm(p + ba_s);
        const float mskE = sGeo[192 + ebase + lnE];
        const float sc = att * mskE;
        #pragma unroll
        for (int t = 0; t < 4; ++t) {
            uint2 st;
            st.x = pk2(m2v[t * 4 + 0] * sc, m2v[t * 4 + 1] * sc);
            st.y = pk2(m2v[t * 4 + 2] * sc, m2v[t * 4 + 3] * sc);
            int phys = (8 + (t << 1) + (q >> 1)) ^ sw;
            *(uint2*)&inpRow[phys * 8 + (q & 1) * 4] = st;
        }
        f32x4 c0 = {0,0,0,0}, c1 = {0,0,0,0}, c2 = {0,0,0,0}, c3 = {0,0,0,0};
        #pragma unroll
        for (int c = 0; c < 2; ++c) {
            bf16x8 b = *(const bf16x8*)&inpRow[((8 + (c << 2) + q) ^ sw) * 8];
            c0 = __builtin_amdgcn_mfma_f32_16x16x32_bf16(sWfA[2048 + (c*4+0)*64 + lane], b, c0, 0,0,0);
            c1 = __builtin_amdgcn_mfma_f32_16x16x32_bf16(sWfA[2048 + (c*4+1)*64 + lane], b, c1, 0,0,0);
            c2 = __builtin_amdgcn_mfma_f32_16x16x32_bf16(sWfA[2048 + (c*4+2)*64 + lane], b, c2, 0,0,0);
            c3 = __builtin_amdgcn_mfma_f32_16x16x32_bf16(sWfA[2048 + (c*4+3)*64 + lane], b, c3, 0,0,0);
        }
        float p3 = 0.0f;
        {
            f32x4 a[4] = {c0, c1, c2, c3};
            #pragma unroll
            for (int t = 0; t < 4; ++t)
                #pragma unroll
                for (int r = 0; r < 4; ++r) {
                    int f = t * 16 + q * 4 + r;
                    p3 = fmaf(silu(a[t][r] + sBias[128 + f]), sBias[256 + f], p3);
                }
        }
        p3 += __shfl_xor(p3, 16, 64);
        p3 += __shfl_xor(p3, 32, 64);
        const float mag = tanh_fast(p3) * mskE;
        if (q == 0) {
            int eg = gbase + ebase + lnE;
            if (eg < E) {
                int ei = ebase + lnE;
                int slot = sSlot[ei];
                disp[slot] = make_float4(sGeo[ei] * mag, sGeo[64 + ei] * mag,
                                         sGeo[128 + ei] * mag, 0.0f);
            }
        }
        // ---- per-wave msg store (own rows only — no barrier needed) ----
        #pragma unroll
        for (int i = 0; i < 2; ++i) {
            int rowL = (lane >> 3) + 8 * i;        // 0..15
            int e = ebase + rowL;
            int off = lane & 7;
            int eg = gbase + e;
            if (eg < E) {
                int phys = (8 + off) ^ (e & 7);
                msg8[(size_t)sSlot[e] * 8 + off] = *(const bf16x8*)&sInp[e * 256 + phys * 8];
            }
        }
        // ---- rotate pipeline registers ----
        #pragma unroll
        for (int i = 0; i < 4; ++i) { hvA[i] = hvB[i]; niB[i] = niC[i]; }
        xdA[0] = xdB[0]; xdA[1] = xdB[1]; xdA[2] = xdB[2];
        xsA[0] = xsB[0]; xsA[1] = xsB[1]; xsA[2] = xsB[2];
        slotA = slotB; dB = dC; sB2 = sC;
    }
}

// --- node kernel: streaming gather + MFMA MLP, swizzled LDS -------------

__global__ __launch_bounds__(256, 2)
void node_kernel(const short* __restrict__ hbf, const float* __restrict__ h,
                 const float* __restrict__ x, const int* __restrict__ off,
                 const short* __restrict__ msg, const float4* __restrict__ disp,
                 const short* __restrict__ wfragN,
                 const float* __restrict__ bh1, const float* __restrict__ bh2,
                 float* __restrict__ hout, float* __restrict__ xout, int N)
{
    __shared__ short sWfN[1536 * 8];     // 24576 B
    __shared__ short sB[64 * 128];       // 16384 B: 16 blocks/row, swizzled
    __shared__ float sOut[64 * 64];      // 16384 B: swizzled fp32
    __shared__ float4 sXdP[64 * 4];      // 4096 B
    __shared__ float sBiasN[2 * 64];

    const int tid  = threadIdx.x;
    const int lane = tid & 63;
    const int wv   = tid >> 6;
    const int lnE  = lane & 15;
    const int q    = lane >> 4;

    {
        const bf16x8* src8 = (const bf16x8*)wfragN;
        bf16x8* dst8 = (bf16x8*)sWfN;
        #pragma unroll
        for (int i = 0; i < 6; ++i) dst8[tid + i * 256] = src8[tid + i * 256];
        if (tid < 64) { sBiasN[tid] = bh1[tid]; sBiasN[64 + tid] = bh2[tid]; }
    }

    const int gbase = blockIdx.x * 64;
    const bf16x8* hb8 = (const bf16x8*)hbf;
    const bf16x8* sWfA = (const bf16x8*)sWfN;
    const uint2* msg_u2 = (const uint2*)msg;

    // --- stage h rows (coalesced, swizzled) ---
    #pragma unroll
    for (int i = 0; i < 2; ++i) {
        int s = tid + i * 256;
        int row = s >> 3, sg = s & 7;
        int nc = gbase + row; if (nc >= N) nc = N - 1;
        bf16x8 v = hb8[(size_t)nc * 8 + sg];
        int phys = sg ^ (row & 7);
        *(bf16x8*)&sB[row * 128 + phys * 8] = v;
    }

    // --- msg gather: lane = (seg c 0..15, slot-offset r 0..3); 2 rows interleaved ---
    const int c = lane & 15;
    const int r = lane >> 4;
    for (int i = 0; i < 16; i += 2) {
        int rowA = wv * 16 + i, rowB = rowA + 1;
        int nA = gbase + rowA; if (nA >= N) nA = N - 1;
        int nB = gbase + rowB; if (nB >= N) nB = N - 1;
        int a0 = off[nA], a1 = off[nA + 1];
        int b0 = off[nB], b1 = off[nB + 1];
        float accA[4] = {0,0,0,0}, accB[4] = {0,0,0,0};
        int ia = a0 + r, ib = b0 + r;
        while (ia < a1 || ib < b1) {
            if (ia < a1) {
                uint2 v = msg_u2[(size_t)ia * 16 + c];
                accA[0] += __uint_as_float(v.x << 16);
                accA[1] += __uint_as_float(v.x & 0xffff0000u);
                accA[2] += __uint_as_float(v.y << 16);
                accA[3] += __uint_as_float(v.y & 0xffff0000u);
            }
            if (ib < b1) {
                uint2 v = msg_u2[(size_t)ib * 16 + c];
                accB[0] += __uint_as_float(v.x << 16);
                accB[1] += __uint_as_float(v.x & 0xffff0000u);
                accB[2] += __uint_as_float(v.y << 16);
                accB[3] += __uint_as_float(v.y & 0xffff0000u);
            }
            ia += 4; ib += 4;
        }
        #pragma unroll
        for (int j = 0; j < 4; ++j) {
            accA[j] += __shfl_xor(accA[j], 16, 64);
            accA[j] += __shfl_xor(accA[j], 32, 64);
            accB[j] += __shfl_xor(accB[j], 16, 64);
            accB[j] += __shfl_xor(accB[j], 32, 64);
        }
        if (r == 0) {
            uint2 stA, stB;
            stA.x = pk2(accA[0], accA[1]); stA.y = pk2(accA[2], accA[3]);
            stB.x = pk2(accB[0], accB[1]); stB.y = pk2(accB[2], accB[3]);
            int pA = (8 + (c >> 1)) ^ (rowA & 7);
            int pB = (8 + (c >> 1)) ^ (rowB & 7);
            *(uint2*)&sB[rowA * 128 + pA * 8 + (c & 1) * 4] = stA;
            *(uint2*)&sB[rowB * 128 + pB * 8 + (c & 1) * 4] = stB;
        }
    }

    // --- disp partial sums: row = tid&63, quarter = tid>>6 ---
    {
        int row = tid & 63, qq = tid >> 6;
        int nc = gbase + row; if (nc >= N) nc = N - 1;
        int r0 = off[nc], r1 = off[nc + 1];
        float dx = 0.0f, dy = 0.0f, dz = 0.0f;
        for (int j = r0 + qq; j < r1; j += 4) {
            float4 d4 = disp[j];
            dx += d4.x; dy += d4.y; dz += d4.z;
        }
        sXdP[row * 4 + qq] = make_float4(dx, dy, dz, 0.0f);
    }
    __syncthreads();

    // --- MFMA MLP ---
    const int myrow = wv * 16 + lnE;
    const int sw = myrow & 7;
    short* bRow = &sB[myrow * 128];

    f32x4 a0 = {0,0,0,0}, a1 = {0,0,0,0}, a2 = {0,0,0,0}, a3 = {0,0,0,0};
    #pragma unroll
    for (int cc = 0; cc < 4; ++cc) {
        bf16x8 b = *(const bf16x8*)&bRow[(((cc << 2) + q) ^ sw) * 8];
        a0 = __builtin_amdgcn_mfma_f32_16x16x32_bf16(sWfA[(cc*4+0)*64 + lane], b, a0, 0,0,0);
        a1 = __builtin_amdgcn_mfma_f32_16x16x32_bf16(sWfA[(cc*4+1)*64 + lane], b, a1, 0,0,0);
        a2 = __builtin_amdgcn_mfma_f32_16x16x32_bf16(sWfA[(cc*4+2)*64 + lane], b, a2, 0,0,0);
        a3 = __builtin_amdgcn_mfma_f32_16x16x32_bf16(sWfA[(cc*4+3)*64 + lane], b, a3, 0,0,0);
    }
    {
        f32x4 a[4] = {a0, a1, a2, a3};
        #pragma unroll
        for (int t = 0; t < 4; ++t) {
            int fb = t * 16 + q * 4;
            uint2 st;
            st.x = pk2(silu(a[t][0] + sBiasN[fb + 0]), silu(a[t][1] + sBiasN[fb + 1]));
            st.y = pk2(silu(a[t][2] + sBiasN[fb + 2]), silu(a[t][3] + sBiasN[fb + 3]));
            int phys = ((t << 1) + (q >> 1)) ^ sw;
            *(uint2*)&bRow[phys * 8 + (q & 1) * 4] = st;
        }
    }
    f32x4 b0 = {0,0,0,0}, b1 = {0,0,0,0}, b2 = {0,0,0,0}, b3 = {0,0,0,0};
    #pragma unroll
    for (int cc = 0; cc < 2; ++cc) {
        bf16x8 b = *(const bf16x8*)&bRow[(((cc << 2) + q) ^ sw) * 8];
        b0 = __builtin_amdgcn_mfma_f32_16x16x32_bf16(sWfA[1024 + (cc*4+0)*64 + lane], b, b0, 0,0,0);
        b1 = __builtin_amdgcn_mfma_f32_16x16x32_bf16(sWfA[1024 + (cc*4+1)*64 + lane], b, b1, 0,0,0);
        b2 = __builtin_amdgcn_mfma_f32_16x16x32_bf16(sWfA[1024 + (cc*4+2)*64 + lane], b, b2, 0,0,0);
        b3 = __builtin_amdgcn_mfma_f32_16x16x32_bf16(sWfA[1024 + (cc*4+3)*64 + lane], b, b3, 0,0,0);
    }
    {
        f32x4 a[4] = {b0, b1, b2, b3};
        #pragma unroll
        for (int t = 0; t < 4; ++t) {
            float v4[4] __attribute__((aligned(16)));
            #pragma unroll
            for (int r2 = 0; r2 < 4; ++r2)
                v4[r2] = a[t][r2] + sBiasN[64 + t * 16 + q * 4 + r2];
            int phys = ((t << 2) + q) ^ sw;
            *(f32x4*)&sOut[myrow * 64 + phys * 4] = *(const f32x4*)v4;
        }
    }
    __syncthreads();

    // --- coalesced stores ---
    #pragma unroll
    for (int i = 0; i < 16; ++i) {
        int s = tid + i * 256;
        int row = s >> 6, f = s & 63;
        int n = gbase + row;
        if (n < N) {
            int phys = ((f >> 2) ^ (row & 7)) * 4 + (f & 3);
            hout[(size_t)n * 64 + f] = h[(size_t)n * 64 + f] + sOut[row * 64 + phys];
        }
    }
    if (tid < 192) {
        int row = tid / 3, comp = tid % 3;
        int n = gbase + row;
        if (n < N) {
            float s = ((const float*)&sXdP[row * 4 + 0])[comp]
                    + ((const float*)&sXdP[row * 4 + 1])[comp]
                    + ((const float*)&sXdP[row * 4 + 2])[comp]
                    + ((const float*)&sXdP[row * 4 + 3])[comp];
            xout[(size_t)n * 3 + comp] = x[(size_t)n * 3 + comp] + s;
        }
    }
}

// --- launch --------------------------------------------------------------

extern "C" void kernel_launch(void* const* d_in, const int* in_sizes, int n_in,
                              void* d_out, int out_size, void* d_ws, size_t ws_size,
                              hipStream_t stream) {
    const float* h    = (const float*)d_in[0];
    const float* x    = (const float*)d_in[1];
    const int*   edst = (const int*)d_in[2];
    const int*   esrc = (const int*)d_in[3];
    const float* means= (const float*)d_in[4];
    const float* stds = (const float*)d_in[5];
    const float* Wm1  = (const float*)d_in[6];
    const float* bm1  = (const float*)d_in[7];
    const float* Wm2  = (const float*)d_in[8];
    const float* bm2  = (const float*)d_in[9];
    const float* Wa   = (const float*)d_in[10];
    const float* ba   = (const float*)d_in[11];
    const float* Wx1  = (const float*)d_in[12];
    const float* bx1  = (const float*)d_in[13];
    const float* Wx2  = (const float*)d_in[14];
    const float* Wh1  = (const float*)d_in[15];
    const float* bh1  = (const float*)d_in[16];
    const float* Wh2  = (const float*)d_in[17];
    const float* bh2  = (const float*)d_in[18];

    const int N = in_sizes[0] / 64;
    const int E = in_sizes[2];
    const int nb = (N + 1023) / 1024;

    float* hout = (float*)d_out;
    float* xout = hout + (size_t)N * 64;

    // workspace layout
    uintptr_t wp = (uintptr_t)d_ws;
    int* counts = (int*)wp;                 wp += (size_t)N * 4;
    int* off    = (int*)wp;                 wp += (size_t)(N + 1) * 4;
    int* cursor = (int*)wp;                 wp += (size_t)N * 4;
    int* local  = (int*)wp;                 wp += (size_t)N * 4;
    int* bsum   = (int*)wp;                 wp += 1024 * 4;
    int* eslot  = (int*)wp;                 wp += (size_t)E * 4;
    wp = (wp + 255) & ~(uintptr_t)255;
    short* msg  = (short*)wp;               wp += (size_t)E * 64 * 2;
    wp = (wp + 255) & ~(uintptr_t)255;
    float4* disp = (float4*)wp;             wp += (size_t)E * 16;
    wp = (wp + 255) & ~(uintptr_t)255;
    short* hbf  = (short*)wp;               wp += (size_t)N * 64 * 2;
    wp = (wp + 255) & ~(uintptr_t)255;
    short* wfrag = (short*)wp;              wp += 4096 * 8 * 2;

    // CSR offsets + per-edge slots
    hipMemsetAsync(counts, 0, (size_t)N * 4, stream);
    hist_kernel<<<(E + 255) / 256, 256, 0, stream>>>(edst, counts, E);
    scan1_kernel<<<nb, 1024, 0, stream>>>(counts, local, bsum, N);
    scan2_kernel<<<1, 1024, 0, stream>>>(bsum, nb);
    scan3_kernel<<<(N + 255) / 256, 256, 0, stream>>>(local, bsum, off, cursor, N, E);
    scatter_kernel<<<(E + 255) / 256, 256, 0, stream>>>(edst, cursor, eslot, E);

    // prestage
    h2bf_kernel<<<(N * 64 + 255) / 256, 256, 0, stream>>>(h, hbf, N * 64);
    wfrag_kernel<<<16, 256, 0, stream>>>(Wm1, Wm2, Wx1, Wh1, Wh2, wfrag);

    // edge pipeline
    const int ngroups = (E + 63) / 64;
    edge_kernel<<<1024, 256, 0, stream>>>(hbf, x, edst, esrc, eslot, means, stds, wfrag,
                                          bm1, bm2, Wa, ba, bx1, Wx2,
                                          msg, disp, E, ngroups);

    // node update
    node_kernel<<<(N + 63) / 64, 256, 0, stream>>>(hbf, h, x, off, msg, disp,
                                                   wfrag + 2560 * 8,
                                                   bh1, bh2, hout, xout, N);
}